// Round 6
// baseline (1200.780 us; speedup 1.0000x reference)
//
#include <hip/hip_runtime.h>
#include <hip/hip_bf16.h>

#define N1 131072
#define E1 2097152
#define N2 2368
#define E2 37888
#define NROIS 148
#define BSZ 16
#define HID 64
#define INCH 128
#define NSEG (BSZ*NROIS)      /* 2368 */
#define SDIM (NROIS*HID)      /* 9472 */
#define CLS 1000
#define OCH 2
#define KC 74                 /* 9472/128: split-K chunk for k_cls */
#define FILL_P 8              /* dst-range passes for graph-1 CSR fill */

// ---------------- CSR build: histogram / scan / fill ----------------

__global__ void k_hist_dst(int* __restrict__ cnt, const int* __restrict__ dst, int E) {
    int e = blockIdx.x * 256 + threadIdx.x;
    if (e < E) atomicAdd(&cnt[dst[e]], 1);
}

__global__ void k_hist_seg(int* __restrict__ cnt, const int* __restrict__ batch,
                           const int* __restrict__ label, int n) {
    int i = blockIdx.x * 256 + threadIdx.x;
    if (i < n) atomicAdd(&cnt[batch[i] * NROIS + label[i]], 1);
}

// multi-block exclusive scan (for N1-sized arrays)
__global__ void k_scan1(const int* __restrict__ in, int* __restrict__ out,
                        int* __restrict__ part, int n) {
    __shared__ int sh[256];
    int t = threadIdx.x;
    int i0 = blockIdx.x * 1024 + t * 4;
    int v0 = (i0     < n) ? in[i0]     : 0;
    int v1 = (i0 + 1 < n) ? in[i0 + 1] : 0;
    int v2 = (i0 + 2 < n) ? in[i0 + 2] : 0;
    int v3 = (i0 + 3 < n) ? in[i0 + 3] : 0;
    int tot = v0 + v1 + v2 + v3;
    sh[t] = tot; __syncthreads();
    for (int off = 1; off < 256; off <<= 1) {
        int x = 0; if (t >= off) x = sh[t - off];
        __syncthreads();
        if (t >= off) sh[t] += x;
        __syncthreads();
    }
    int excl = sh[t] - tot;
    if (t == 255) part[blockIdx.x] = sh[255];
    if (i0     < n) out[i0]     = excl;
    if (i0 + 1 < n) out[i0 + 1] = excl + v0;
    if (i0 + 2 < n) out[i0 + 2] = excl + v0 + v1;
    if (i0 + 3 < n) out[i0 + 3] = excl + v0 + v1 + v2;
}

__global__ void k_scan2(int* __restrict__ part, int cnt) {
    __shared__ int sh[256];
    int t = threadIdx.x;
    int v = (t < cnt) ? part[t] : 0;
    sh[t] = v; __syncthreads();
    for (int off = 1; off < 256; off <<= 1) {
        int x = 0; if (t >= off) x = sh[t - off];
        __syncthreads();
        if (t >= off) sh[t] += x;
        __syncthreads();
    }
    if (t < cnt) part[t] = sh[t] - v;
}

__global__ void k_scan3(int* __restrict__ out, const int* __restrict__ part, int n, int total) {
    int i = blockIdx.x * 256 + threadIdx.x;
    if (i < n) out[i] += part[i >> 10];
    if (i == 0) out[n] = total;
}

// single-block exclusive scan for small arrays; writes sentinel out[n]
__global__ void k_scan_one(const int* __restrict__ in, int* __restrict__ out, int n) {
    __shared__ int sh[256];
    __shared__ int carry;
    int t = threadIdx.x;
    if (t == 0) carry = 0;
    __syncthreads();
    for (int base = 0; base < n; base += 256) {
        int i = base + t;
        int v = (i < n) ? in[i] : 0;
        sh[t] = v; __syncthreads();
        for (int off = 1; off < 256; off <<= 1) {
            int x = 0; if (t >= off) x = sh[t - off];
            __syncthreads();
            if (t >= off) sh[t] += x;
            __syncthreads();
        }
        if (i < n) out[i] = carry + sh[t] - v;
        __syncthreads();
        if (t == 255) carry += sh[255];
        __syncthreads();
    }
    if (t == 0) out[n] = carry;
}

// fill CSR with (src, weight) pairs — only edges whose dst falls in [lo,hi).
// Range passes keep the scatter window L2-resident (write-back once).
__global__ void k_fill_edges(int2* __restrict__ edges, int* __restrict__ off,
                             const int* __restrict__ src, const int* __restrict__ dst,
                             const float* __restrict__ ew, int E, int lo, int hi) {
    int e = blockIdx.x * 256 + threadIdx.x;
    if (e >= E) return;
    int d = dst[e];
    if (d < lo || d >= hi) return;
    int pos = atomicAdd(&off[d], 1);
    edges[pos] = make_int2(src[e], __float_as_int(ew[e]));
}

__global__ void k_fill_seg(int* __restrict__ nodeid, int* __restrict__ off,
                           const int* __restrict__ batch, const int* __restrict__ label, int n) {
    int i = blockIdx.x * 256 + threadIdx.x;
    if (i >= n) return;
    int pos = atomicAdd(&off[batch[i] * NROIS + label[i]], 1);
    nodeid[pos] = i;
}

// dinv[d] = rsqrt(1 + sum of in-edge weights)
__global__ void k_deg_dinv(float* __restrict__ dinv, const int* __restrict__ row,
                           const int2* __restrict__ edges, int n) {
    int d = blockIdx.x * 256 + threadIdx.x;
    if (d >= n) return;
    int a = row[d], b = row[d + 1];
    float s = 1.0f;
    for (int i = a; i < b; i++) s += __int_as_float(edges[i].y);
    dinv[d] = rsqrtf(s);
}

// edge.w = dinv[src]*w*dinv[dst], in place
__global__ void k_scale(int2* __restrict__ edges, const int* __restrict__ row,
                        const float* __restrict__ dinv, int n) {
    int d = blockIdx.x * 256 + threadIdx.x;
    if (d >= n) return;
    int a = row[d], b = row[d + 1];
    float dd = dinv[d];
    for (int i = a; i < b; i++) {
        int2 e = edges[i];
        edges[i].y = __float_as_int(dinv[e.x] * __int_as_float(e.y) * dd);
    }
}

// fused CSR build for the small graph: hist + scan + fill + dinv + scale, one block.
__global__ __launch_bounds__(256) void k_build_small(int* __restrict__ row,
                                                     int2* __restrict__ edges,
                                                     float* __restrict__ dinv,
                                                     const int* __restrict__ src,
                                                     const int* __restrict__ dst,
                                                     const float* __restrict__ ew) {
    __shared__ int cnt[N2];
    __shared__ int rowl[N2 + 1];
    __shared__ float dl[N2];
    __shared__ int sh[256];
    __shared__ int carry;
    int t = threadIdx.x;
    for (int i = t; i < N2; i += 256) cnt[i] = 0;
    if (t == 0) carry = 0;
    __syncthreads();
    for (int e = t; e < E2; e += 256) atomicAdd(&cnt[dst[e]], 1);
    __syncthreads();
    for (int base = 0; base < N2; base += 256) {
        int i = base + t;
        int v = (i < N2) ? cnt[i] : 0;
        sh[t] = v; __syncthreads();
        for (int off = 1; off < 256; off <<= 1) {
            int x = 0; if (t >= off) x = sh[t - off];
            __syncthreads();
            if (t >= off) sh[t] += x;
            __syncthreads();
        }
        if (i < N2) rowl[i] = carry + sh[t] - v;
        __syncthreads();
        if (t == 255) carry += sh[255];
        __syncthreads();
    }
    if (t == 0) rowl[N2] = E2;
    __syncthreads();
    for (int i = t; i < N2; i += 256) cnt[i] = rowl[i];       // off = row start
    for (int i = t; i < N2 + 1; i += 256) row[i] = rowl[i];   // export rowptr
    __syncthreads();
    for (int e = t; e < E2; e += 256) {
        int d = dst[e];
        int pos = atomicAdd(&cnt[d], 1);
        edges[pos] = make_int2(src[e], __float_as_int(ew[e]));
    }
    __syncthreads();
    for (int d = t; d < N2; d += 256) {
        int a = rowl[d], b = rowl[d + 1];
        float s = 1.0f;
        for (int i = a; i < b; i++) s += __int_as_float(edges[i].y);
        float di = rsqrtf(s);
        dl[d] = di;
        dinv[d] = di;
    }
    __syncthreads();
    for (int d = t; d < N2; d += 256) {
        int a = rowl[d], b = rowl[d + 1];
        float dd = dl[d];
        for (int i = a; i < b; i++) {
            int2 e = edges[i];
            edges[i].y = __float_as_int(dl[e.x] * __int_as_float(e.y) * dd);
        }
    }
}

// fused segment-CSR build for small n: hist + scan + fill, one block.
__global__ __launch_bounds__(256) void k_build_seg_small(int* __restrict__ segrow,
                                                         int* __restrict__ nodeid,
                                                         const int* __restrict__ batch,
                                                         const int* __restrict__ label, int n) {
    __shared__ int cnt[NSEG];
    __shared__ int rowl[NSEG + 1];
    __shared__ int sh[256];
    __shared__ int carry;
    int t = threadIdx.x;
    for (int i = t; i < NSEG; i += 256) cnt[i] = 0;
    if (t == 0) carry = 0;
    __syncthreads();
    for (int i = t; i < n; i += 256) atomicAdd(&cnt[batch[i] * NROIS + label[i]], 1);
    __syncthreads();
    for (int base = 0; base < NSEG; base += 256) {
        int i = base + t;
        int v = (i < NSEG) ? cnt[i] : 0;
        sh[t] = v; __syncthreads();
        for (int off = 1; off < 256; off <<= 1) {
            int x = 0; if (t >= off) x = sh[t - off];
            __syncthreads();
            if (t >= off) sh[t] += x;
            __syncthreads();
        }
        if (i < NSEG) rowl[i] = carry + sh[t] - v;
        __syncthreads();
        if (t == 255) carry += sh[255];
        __syncthreads();
    }
    if (t == 0) rowl[NSEG] = n;
    __syncthreads();
    for (int i = t; i < NSEG; i += 256) cnt[i] = rowl[i];
    for (int i = t; i < NSEG + 1; i += 256) segrow[i] = rowl[i];
    __syncthreads();
    for (int i = t; i < n; i += 256) {
        int pos = atomicAdd(&cnt[batch[i] * NROIS + label[i]], 1);
        nodeid[pos] = i;
    }
}

// ---------------- dense ops ----------------

// out[n][64] = x[n][K] @ W[K][64]. Block: 256 rows x 64 cols; thread tile 8x8.
template <int K>
__global__ __launch_bounds__(256) void k_gemm(float* __restrict__ out,
                                              const float* __restrict__ x,
                                              const float* __restrict__ W, int n) {
    __shared__ float Wl[32 * 64];       // [kk][col]
    __shared__ float xs[256 * 37];      // [r][kk], stride 37
    int tid = threadIdx.x;
    int row0 = blockIdx.x * 256;
    int r0 = (tid >> 3) * 8;
    int c0 = (tid & 7) * 8;
    float acc[8][8];
#pragma unroll
    for (int i = 0; i < 8; i++)
#pragma unroll
        for (int j = 0; j < 8; j++) acc[i][j] = 0.f;

    for (int k0 = 0; k0 < K; k0 += 32) {
        __syncthreads();
        {
            const float4* W4 = (const float4*)(W + k0 * 64);
            float4* Wl4 = (float4*)Wl;
#pragma unroll
            for (int i = 0; i < 2; i++) Wl4[tid + i * 256] = W4[tid + i * 256];
        }
#pragma unroll
        for (int i = 0; i < 8; i++) {
            int idx = tid + i * 256;
            int r = idx >> 3, kq = idx & 7;
            float4 v = make_float4(0.f, 0.f, 0.f, 0.f);
            if (row0 + r < n)
                v = *(const float4*)(x + (size_t)(row0 + r) * K + k0 + kq * 4);
            xs[r * 37 + kq * 4 + 0] = v.x;
            xs[r * 37 + kq * 4 + 1] = v.y;
            xs[r * 37 + kq * 4 + 2] = v.z;
            xs[r * 37 + kq * 4 + 3] = v.w;
        }
        __syncthreads();
#pragma unroll 2
        for (int kk = 0; kk < 32; kk++) {
            float4 wlo = *(const float4*)(&Wl[kk * 64 + c0]);
            float4 whi = *(const float4*)(&Wl[kk * 64 + c0 + 4]);
            float xf[8];
#pragma unroll
            for (int i = 0; i < 8; i++) xf[i] = xs[(r0 + i) * 37 + kk];
#pragma unroll
            for (int i = 0; i < 8; i++) {
                acc[i][0] += xf[i] * wlo.x; acc[i][1] += xf[i] * wlo.y;
                acc[i][2] += xf[i] * wlo.z; acc[i][3] += xf[i] * wlo.w;
                acc[i][4] += xf[i] * whi.x; acc[i][5] += xf[i] * whi.y;
                acc[i][6] += xf[i] * whi.z; acc[i][7] += xf[i] * whi.w;
            }
        }
    }
#pragma unroll
    for (int i = 0; i < 8; i++) {
        int row = row0 + r0 + i;
        if (row < n) {
            *(float4*)(&out[(size_t)row * 64 + c0]) =
                make_float4(acc[i][0], acc[i][1], acc[i][2], acc[i][3]);
            *(float4*)(&out[(size_t)row * 64 + c0 + 4]) =
                make_float4(acc[i][4], acc[i][5], acc[i][6], acc[i][7]);
        }
    }
}

// fused GCN aggregate: wave per dst node, lane = feature column, 8-deep ILP.
__global__ __launch_bounds__(256) void k_conv(float* __restrict__ out, const float* __restrict__ h,
                                              const int2* __restrict__ edges,
                                              const int* __restrict__ row,
                                              const float* __restrict__ dinv,
                                              const float* __restrict__ bias, int n) {
    int d = blockIdx.x * 4 + (threadIdx.x >> 6);
    if (d >= n) return;
    int lane = threadIdx.x & 63;
    int a = row[d], b = row[d + 1];
    float acc[8] = {0.f, 0.f, 0.f, 0.f, 0.f, 0.f, 0.f, 0.f};
    for (int base = a; base < b; base += 64) {
        int m = b - base; if (m > 64) m = 64;
        int sv = 0, wv = 0;
        if (base + lane < b) { int2 e = edges[base + lane]; sv = e.x; wv = e.y; }
        int j = 0;
        for (; j + 7 < m; j += 8) {
#pragma unroll
            for (int q = 0; q < 8; q++) {
                int s = __shfl(sv, j + q);
                float w = __int_as_float(__shfl(wv, j + q));
                acc[q] += h[(size_t)s * HID + lane] * w;
            }
        }
        for (; j < m; j++) {
            int s = __shfl(sv, j);
            float w = __int_as_float(__shfl(wv, j));
            acc[0] += h[(size_t)s * HID + lane] * w;
        }
    }
    float di = dinv[d];
    float v = ((acc[0] + acc[1]) + (acc[2] + acc[3])) + ((acc[4] + acc[5]) + (acc[6] + acc[7]))
              + h[(size_t)d * HID + lane] * di * di + bias[lane];
    out[(size_t)d * HID + lane] = v > 0.f ? v : 0.f;
}

// segment-mean pool: wave per segment; counts from rowptr diff.
__global__ __launch_bounds__(256) void k_pool(float* __restrict__ emb, float* __restrict__ esum,
                                              const float* __restrict__ embo,
                                              const float* __restrict__ h,
                                              const int* __restrict__ nodeid,
                                              const int* __restrict__ segrow) {
    int s = blockIdx.x * 4 + (threadIdx.x >> 6);
    if (s >= NSEG) return;
    int lane = threadIdx.x & 63;
    int a = segrow[s], b = segrow[s + 1];
    float ac0 = 0.f, ac1 = 0.f, ac2 = 0.f, ac3 = 0.f;
    for (int base = a; base < b; base += 64) {
        int m = b - base; if (m > 64) m = 64;
        int nid = 0;
        if (base + lane < b) nid = nodeid[base + lane];
        int j = 0;
        for (; j + 3 < m; j += 4) {
            int n0 = __shfl(nid, j),     n1 = __shfl(nid, j + 1);
            int n2 = __shfl(nid, j + 2), n3 = __shfl(nid, j + 3);
            ac0 += h[(size_t)n0 * HID + lane];
            ac1 += h[(size_t)n1 * HID + lane];
            ac2 += h[(size_t)n2 * HID + lane];
            ac3 += h[(size_t)n3 * HID + lane];
        }
        for (; j < m; j++) {
            int n0 = __shfl(nid, j);
            ac0 += h[(size_t)n0 * HID + lane];
        }
    }
    float mean = ((ac0 + ac1) + (ac2 + ac3)) / fmaxf((float)(b - a), 1.0f);
    emb[(size_t)s * HID + lane] = mean;
    if (esum) esum[(size_t)s * HID + lane] = mean + embo[(size_t)s * HID + lane];
}

// ---------------- classifier ----------------

__global__ __launch_bounds__(256) void k_cls(float* __restrict__ hcls,
                                             const float* __restrict__ s,
                                             const float* __restrict__ Wm1) {
    __shared__ float sl[KC * 16];
    int tid = threadIdx.x;
    int k0 = blockIdx.x * KC;
    for (int i = tid; i < KC * 16; i += 256) {
        int kk = i >> 4, b = i & 15;
        sl[i] = s[b * SDIM + k0 + kk];
    }
    __syncthreads();
    int c4 = tid * 4;
    bool active = c4 < CLS;
    const float zero4[4] = {0.f, 0.f, 0.f, 0.f};
    float4 acc[16];
#pragma unroll
    for (int b = 0; b < 16; b++) acc[b] = make_float4(0.f, 0.f, 0.f, 0.f);
    for (int kk = 0; kk < KC; kk++) {
        float4 w = active ? *(const float4*)(&Wm1[(size_t)(k0 + kk) * CLS + c4])
                          : *(const float4*)zero4;
#pragma unroll
        for (int b = 0; b < 16; b++) {
            float sv = sl[kk * 16 + b];
            acc[b].x += sv * w.x; acc[b].y += sv * w.y;
            acc[b].z += sv * w.z; acc[b].w += sv * w.w;
        }
    }
    if (active) {
#pragma unroll
        for (int b = 0; b < 16; b++) {
            unsafeAtomicAdd(&hcls[b * CLS + c4 + 0], acc[b].x);
            unsafeAtomicAdd(&hcls[b * CLS + c4 + 1], acc[b].y);
            unsafeAtomicAdd(&hcls[b * CLS + c4 + 2], acc[b].z);
            unsafeAtomicAdd(&hcls[b * CLS + c4 + 3], acc[b].w);
        }
    }
}

__global__ void k_bn(float* __restrict__ hact, const float* __restrict__ hcls,
                     const float* __restrict__ bm1, const float* __restrict__ gamma,
                     const float* __restrict__ beta, const float* __restrict__ mean,
                     const float* __restrict__ var) {
    int i = blockIdx.x * blockDim.x + threadIdx.x;
    if (i >= BSZ * CLS) return;
    int j = i % CLS;
    float t = hcls[i] + bm1[j];
    t = gamma[j] * (t - mean[j]) * rsqrtf(var[j] + 1e-5f) + beta[j];
    hact[i] = t > 0.f ? t : 0.01f * t;
}

__global__ void k_out(float* __restrict__ outp, const float* __restrict__ hact,
                      const float* __restrict__ Wm2, const float* __restrict__ bm2) {
    int tid = threadIdx.x;              // one block of 256
    int oi = tid >> 3, part = tid & 7;  // 32 outputs x 8 partials
    int b = oi >> 1, o = oi & 1;
    float acc = (part == 0) ? bm2[o] : 0.f;
    for (int k = part; k < CLS; k += 8) acc += hact[b * CLS + k] * Wm2[k * OCH + o];
    unsafeAtomicAdd(&outp[b * OCH + o], acc);
}

extern "C" void kernel_launch(void* const* d_in, const int* in_sizes, int n_in,
                              void* d_out, int out_size, void* d_ws, size_t ws_size,
                              hipStream_t stream) {
    const float* x1  = (const float*)d_in[0];
    const int*   nl  = (const int*)d_in[1];
    const int*   ei1 = (const int*)d_in[2];
    const float* ew1 = (const float*)d_in[3];
    const int*   ba1 = (const int*)d_in[4];
    const float* x2  = (const float*)d_in[5];
    const int*   rl  = (const int*)d_in[6];
    const int*   ei2 = (const int*)d_in[7];
    const float* ew2 = (const float*)d_in[8];
    const int*   ba2 = (const int*)d_in[9];
    const float* W1a = (const float*)d_in[10];
    const float* b1a = (const float*)d_in[11];
    const float* W1b = (const float*)d_in[12];
    const float* b1b = (const float*)d_in[13];
    const float* W2a = (const float*)d_in[14];
    const float* b2a = (const float*)d_in[15];
    const float* W2b = (const float*)d_in[16];
    const float* b2b = (const float*)d_in[17];
    const float* Wm1 = (const float*)d_in[18];
    const float* bm1 = (const float*)d_in[19];
    const float* gam = (const float*)d_in[20];
    const float* bet = (const float*)d_in[21];
    const float* bmn = (const float*)d_in[22];
    const float* bvr = (const float*)d_in[23];
    const float* Wm2 = (const float*)d_in[24];
    const float* bm2 = (const float*)d_in[25];

    float* out  = (float*)d_out;
    float* emb1 = out + 32;               // embedding        (16 x 9472)
    float* emb2 = emb1 + NSEG * HID;      // embedding_roi
    float* esum = emb2 + NSEG * HID;      // embedding + embedding_roi

    // ---- workspace carve ----
    char* p = (char*)d_ws;
    auto carve = [&](size_t nbytes) { char* q = p; p += (nbytes + 255) & ~(size_t)255; return (void*)q; };
    int*   row1    = (int*)  carve((N1 + 1) * 4);
    int*   off1    = (int*)  carve(N1 * 4);
    int2*  edges1  = (int2*) carve((size_t)E1 * 8);
    float* dinv1   = (float*)carve(N1 * 4);
    float* A1      = (float*)carve((size_t)N1 * HID * 4);
    float* B1      = (float*)carve((size_t)N1 * HID * 4);
    int*   nodeid1 = (int*)  carve(N1 * 4);
    int*   segrow1 = (int*)  carve((NSEG + 1) * 4);
    int*   segoff1 = (int*)  carve(NSEG * 4);
    int*   row2    = (int*)  carve((N2 + 1) * 4);
    int2*  edges2  = (int2*) carve((size_t)E2 * 8);
    float* dinv2   = (float*)carve(N2 * 4);
    float* A2      = (float*)carve((size_t)N2 * HID * 4);
    float* B2      = (float*)carve((size_t)N2 * HID * 4);
    int*   nodeid2 = (int*)  carve(N2 * 4);
    int*   segrow2 = (int*)  carve((NSEG + 1) * 4);
    int*   part    = (int*)  carve(256 * 4);
    float* hcls    = (float*)carve(BSZ * CLS * 4);
    float* hact    = (float*)carve(BSZ * CLS * 4);

    const int* src1 = ei1;
    const int* dst1 = ei1 + E1;
    const int* src2 = ei2;
    const int* dst2 = ei2 + E2;

    hipMemsetAsync(d_out, 0, (size_t)out_size * sizeof(float), stream);
    hipMemsetAsync(hcls, 0, BSZ * CLS * sizeof(float), stream);

    // ---------------- graph 2 (ROI graph, small; fused builders) ----------------
    k_build_small<<<1, 256, 0, stream>>>(row2, edges2, dinv2, src2, dst2, ew2);

    k_gemm<INCH><<<(N2 + 255) / 256, 256, 0, stream>>>(A2, x2, W2a, N2);
    k_conv<<<(N2 + 3) / 4, 256, 0, stream>>>(B2, A2, edges2, row2, dinv2, b2a, N2);
    k_gemm<HID><<<(N2 + 255) / 256, 256, 0, stream>>>(A2, B2, W2b, N2);
    k_conv<<<(N2 + 3) / 4, 256, 0, stream>>>(B2, A2, edges2, row2, dinv2, b2b, N2);
    // graph-2 final features now in B2

    k_build_seg_small<<<1, 256, 0, stream>>>(segrow2, nodeid2, ba2, rl, N2);
    k_pool<<<(NSEG + 3) / 4, 256, 0, stream>>>(emb2, (float*)nullptr, (const float*)nullptr,
                                               B2, nodeid2, segrow2);

    // ---------------- graph 1 (fine-grained, large) ----------------
    hipMemsetAsync(off1, 0, N1 * 4, stream);
    k_hist_dst<<<(E1 + 255) / 256, 256, 0, stream>>>(off1, dst1, E1);
    k_scan1<<<(N1 + 1023) / 1024, 256, 0, stream>>>(off1, row1, part, N1);
    k_scan2<<<1, 256, 0, stream>>>(part, (N1 + 1023) / 1024);
    k_scan3<<<(N1 + 255) / 256, 256, 0, stream>>>(row1, part, N1, E1);
    hipMemcpyAsync(off1, row1, N1 * 4, hipMemcpyDeviceToDevice, stream);
    for (int pass = 0; pass < FILL_P; pass++) {
        int lo = pass * (N1 / FILL_P), hi = lo + (N1 / FILL_P);
        k_fill_edges<<<(E1 + 255) / 256, 256, 0, stream>>>(edges1, off1, src1, dst1, ew1,
                                                           E1, lo, hi);
    }
    k_deg_dinv<<<(N1 + 255) / 256, 256, 0, stream>>>(dinv1, row1, edges1, N1);
    k_scale<<<(N1 + 255) / 256, 256, 0, stream>>>(edges1, row1, dinv1, N1);

    k_gemm<INCH><<<N1 / 256, 256, 0, stream>>>(A1, x1, W1a, N1);
    k_conv<<<(N1 + 3) / 4, 256, 0, stream>>>(B1, A1, edges1, row1, dinv1, b1a, N1);
    k_gemm<HID><<<N1 / 256, 256, 0, stream>>>(A1, B1, W1b, N1);
    k_conv<<<(N1 + 3) / 4, 256, 0, stream>>>(B1, A1, edges1, row1, dinv1, b1b, N1);

    hipMemsetAsync(segoff1, 0, NSEG * 4, stream);
    k_hist_seg<<<(N1 + 255) / 256, 256, 0, stream>>>(segoff1, ba1, nl, N1);
    k_scan_one<<<1, 256, 0, stream>>>(segoff1, segrow1, NSEG);
    hipMemcpyAsync(segoff1, segrow1, NSEG * 4, hipMemcpyDeviceToDevice, stream);
    k_fill_seg<<<(N1 + 255) / 256, 256, 0, stream>>>(nodeid1, segoff1, ba1, nl, N1);
    k_pool<<<(NSEG + 3) / 4, 256, 0, stream>>>(emb1, esum, emb2, B1, nodeid1, segrow1);

    // ---------------- classifier ----------------
    k_cls<<<SDIM / KC, 256, 0, stream>>>(hcls, esum, Wm1);
    k_bn<<<(BSZ * CLS + 255) / 256, 256, 0, stream>>>(hact, hcls, bm1, gam, bet, bmn, bvr);
    k_out<<<1, 256, 0, stream>>>(out, hact, Wm2, bm2);
}

// Round 7
// 789.390 us; speedup vs baseline: 1.5211x; 1.5211x over previous
//
#include <hip/hip_runtime.h>
#include <hip/hip_bf16.h>

#define N1 131072
#define E1 2097152
#define N2 2368
#define E2 37888
#define NROIS 148
#define BSZ 16
#define HID 64
#define INCH 128
#define NSEG (BSZ*NROIS)      /* 2368 */
#define SDIM (NROIS*HID)      /* 9472 */
#define CLS 1000
#define OCH 2
#define KC 74                 /* 9472/128: split-K chunk for k_cls */

#define NB1 512               /* dst buckets for graph-1 partition */
#define BLK1 512              /* partition blocks */
#define EPB (E1/BLK1)         /* 4096 edges per block */
#define NPB (N1/NB1)          /* 256 nodes per bucket */

// ---------------- generic small-graph CSR build ----------------

__global__ void k_hist_dst(int* __restrict__ cnt, const int* __restrict__ dst, int E) {
    int e = blockIdx.x * 256 + threadIdx.x;
    if (e < E) atomicAdd(&cnt[dst[e]], 1);
}

__global__ void k_hist_seg(int* __restrict__ cnt, const int* __restrict__ batch,
                           const int* __restrict__ label, int n) {
    int i = blockIdx.x * 256 + threadIdx.x;
    if (i < n) atomicAdd(&cnt[batch[i] * NROIS + label[i]], 1);
}

// multi-block exclusive scan
__global__ void k_scan1(const int* __restrict__ in, int* __restrict__ out,
                        int* __restrict__ part, int n) {
    __shared__ int sh[256];
    int t = threadIdx.x;
    int i0 = blockIdx.x * 1024 + t * 4;
    int v0 = (i0     < n) ? in[i0]     : 0;
    int v1 = (i0 + 1 < n) ? in[i0 + 1] : 0;
    int v2 = (i0 + 2 < n) ? in[i0 + 2] : 0;
    int v3 = (i0 + 3 < n) ? in[i0 + 3] : 0;
    int tot = v0 + v1 + v2 + v3;
    sh[t] = tot; __syncthreads();
    for (int off = 1; off < 256; off <<= 1) {
        int x = 0; if (t >= off) x = sh[t - off];
        __syncthreads();
        if (t >= off) sh[t] += x;
        __syncthreads();
    }
    int excl = sh[t] - tot;
    if (t == 255) part[blockIdx.x] = sh[255];
    if (i0     < n) out[i0]     = excl;
    if (i0 + 1 < n) out[i0 + 1] = excl + v0;
    if (i0 + 2 < n) out[i0 + 2] = excl + v0 + v1;
    if (i0 + 3 < n) out[i0 + 3] = excl + v0 + v1 + v2;
}

__global__ void k_scan2(int* __restrict__ part, int cnt) {
    __shared__ int sh[256];
    int t = threadIdx.x;
    int v = (t < cnt) ? part[t] : 0;
    sh[t] = v; __syncthreads();
    for (int off = 1; off < 256; off <<= 1) {
        int x = 0; if (t >= off) x = sh[t - off];
        __syncthreads();
        if (t >= off) sh[t] += x;
        __syncthreads();
    }
    if (t < cnt) part[t] = sh[t] - v;
}

__global__ void k_scan3(int* __restrict__ out, const int* __restrict__ part, int n, int total) {
    int i = blockIdx.x * 256 + threadIdx.x;
    if (i < n) out[i] += part[i >> 10];
    if (i == 0) out[n] = total;
}

// single-block exclusive scan for small arrays; writes sentinel out[n]
__global__ void k_scan_one(const int* __restrict__ in, int* __restrict__ out, int n) {
    __shared__ int sh[256];
    __shared__ int carry;
    int t = threadIdx.x;
    if (t == 0) carry = 0;
    __syncthreads();
    for (int base = 0; base < n; base += 256) {
        int i = base + t;
        int v = (i < n) ? in[i] : 0;
        sh[t] = v; __syncthreads();
        for (int off = 1; off < 256; off <<= 1) {
            int x = 0; if (t >= off) x = sh[t - off];
            __syncthreads();
            if (t >= off) sh[t] += x;
            __syncthreads();
        }
        if (i < n) out[i] = carry + sh[t] - v;
        __syncthreads();
        if (t == 255) carry += sh[255];
        __syncthreads();
    }
    if (t == 0) out[n] = carry;
}

__global__ void k_fill_edges(int2* __restrict__ edges, int* __restrict__ off,
                             const int* __restrict__ src, const int* __restrict__ dst,
                             const float* __restrict__ ew, int E) {
    int e = blockIdx.x * 256 + threadIdx.x;
    if (e >= E) return;
    int pos = atomicAdd(&off[dst[e]], 1);
    edges[pos] = make_int2(src[e], __float_as_int(ew[e]));
}

__global__ void k_fill_seg(int* __restrict__ nodeid, int* __restrict__ off,
                           const int* __restrict__ batch, const int* __restrict__ label, int n) {
    int i = blockIdx.x * 256 + threadIdx.x;
    if (i >= n) return;
    int pos = atomicAdd(&off[batch[i] * NROIS + label[i]], 1);
    nodeid[pos] = i;
}

__global__ void k_deg_dinv(float* __restrict__ dinv, const int* __restrict__ row,
                           const int2* __restrict__ edges, int n) {
    int d = blockIdx.x * 256 + threadIdx.x;
    if (d >= n) return;
    int a = row[d], b = row[d + 1];
    float s = 1.0f;
    for (int i = a; i < b; i++) s += __int_as_float(edges[i].y);
    dinv[d] = rsqrtf(s);
}

__global__ void k_scale(int2* __restrict__ edges, const int* __restrict__ row,
                        const float* __restrict__ dinv, int n) {
    int d = blockIdx.x * 256 + threadIdx.x;
    if (d >= n) return;
    int a = row[d], b = row[d + 1];
    float dd = dinv[d];
    for (int i = a; i < b; i++) {
        int2 e = edges[i];
        edges[i].y = __float_as_int(dinv[e.x] * __int_as_float(e.y) * dd);
    }
}

// ---------------- graph-1 radix-partition CSR build ----------------
// Goal: every cache line of tmp/edges is written by exactly one block (no
// cross-XCD line sharing -> write back once, kills the 8x WRITE amplification).

// P1: per-block histogram of 512 dst-buckets over its 4096-edge chunk.
__global__ __launch_bounds__(256) void k_p1(int* __restrict__ bh, const int* __restrict__ dst) {
    __shared__ int cnt[NB1];
    int t = threadIdx.x, blk = blockIdx.x;
    for (int i = t; i < NB1; i += 256) cnt[i] = 0;
    __syncthreads();
    int base = blk * EPB;
    for (int i = t; i < EPB; i += 256) atomicAdd(&cnt[dst[base + i] >> 8], 1);
    __syncthreads();
    for (int b = t; b < NB1; b += 256) bh[b * BLK1 + blk] = cnt[b];   // bucket-major
}

// P2: partition edges into bucket-contiguous, block-exclusive tmp regions.
// pack = src (17 bits) | dst_local (8 bits) << 17
__global__ __launch_bounds__(256) void k_p2(int2* __restrict__ tmp, const int* __restrict__ obh,
                                            const int* __restrict__ src,
                                            const int* __restrict__ dst,
                                            const float* __restrict__ ew) {
    __shared__ int cur[NB1];
    int t = threadIdx.x, blk = blockIdx.x;
    for (int b = t; b < NB1; b += 256) cur[b] = obh[b * BLK1 + blk];
    __syncthreads();
    int base = blk * EPB;
    for (int i = t; i < EPB; i += 256) {
        int e = base + i;
        int d = dst[e];
        int pos = atomicAdd(&cur[d >> 8], 1);
        tmp[pos] = make_int2(src[e] | ((d & 255) << 17), __float_as_int(ew[e]));
    }
}

// P3a: per-bucket node histogram + edge-weight sums -> deg, dinv.
__global__ __launch_bounds__(256) void k_p3a(int* __restrict__ deg, float* __restrict__ dinv,
                                             const int2* __restrict__ tmp,
                                             const int* __restrict__ obh) {
    __shared__ int h[NPB];
    __shared__ float ws[NPB];
    int t = threadIdx.x, b = blockIdx.x;
    for (int i = t; i < NPB; i += 256) { h[i] = 0; ws[i] = 0.f; }
    __syncthreads();
    int a  = obh[b * BLK1];
    int e_ = (b == NB1 - 1) ? E1 : obh[(b + 1) * BLK1];
    for (int i = a + t; i < e_; i += 256) {
        int2 ed = tmp[i];
        int dl = (ed.x >> 17) & 255;
        atomicAdd(&h[dl], 1);
        atomicAdd(&ws[dl], __int_as_float(ed.y));
    }
    __syncthreads();
    for (int i = t; i < NPB; i += 256) {
        deg[b * NPB + i] = h[i];
        dinv[b * NPB + i] = rsqrtf(1.f + ws[i]);
    }
}

// P3b: final CSR placement (LDS cursors, block-exclusive window) + normalize.
__global__ __launch_bounds__(256) void k_p3b(int2* __restrict__ edges,
                                             const int2* __restrict__ tmp,
                                             const int* __restrict__ obh,
                                             const int* __restrict__ row,
                                             const float* __restrict__ dinv) {
    __shared__ int cur[NPB];
    __shared__ float dvl[NPB];
    int t = threadIdx.x, b = blockIdx.x;
    int n0 = b * NPB;
    for (int i = t; i < NPB; i += 256) {
        cur[i] = row[n0 + i];
        dvl[i] = dinv[n0 + i];
    }
    __syncthreads();
    int a  = obh[b * BLK1];
    int e_ = (b == NB1 - 1) ? E1 : obh[(b + 1) * BLK1];
    for (int i = a + t; i < e_; i += 256) {
        int2 ed = tmp[i];
        int dl = (ed.x >> 17) & 255;
        int s = ed.x & 0x1FFFF;
        int pos = atomicAdd(&cur[dl], 1);
        float w = dinv[s] * __int_as_float(ed.y) * dvl[dl];
        edges[pos] = make_int2(s, __float_as_int(w));
    }
}

// ---------------- dense ops ----------------

// out[n][64] = x[n][K] @ W[K][64]. Block: 256 rows x 64 cols; thread tile 8x8.
template <int K>
__global__ __launch_bounds__(256) void k_gemm(float* __restrict__ out,
                                              const float* __restrict__ x,
                                              const float* __restrict__ W, int n) {
    __shared__ float Wl[32 * 64];       // [kk][col]
    __shared__ float xs[256 * 37];      // [r][kk], stride 37
    int tid = threadIdx.x;
    int row0 = blockIdx.x * 256;
    int r0 = (tid >> 3) * 8;
    int c0 = (tid & 7) * 8;
    float acc[8][8];
#pragma unroll
    for (int i = 0; i < 8; i++)
#pragma unroll
        for (int j = 0; j < 8; j++) acc[i][j] = 0.f;

    for (int k0 = 0; k0 < K; k0 += 32) {
        __syncthreads();
        {
            const float4* W4 = (const float4*)(W + k0 * 64);
            float4* Wl4 = (float4*)Wl;
#pragma unroll
            for (int i = 0; i < 2; i++) Wl4[tid + i * 256] = W4[tid + i * 256];
        }
#pragma unroll
        for (int i = 0; i < 8; i++) {
            int idx = tid + i * 256;
            int r = idx >> 3, kq = idx & 7;
            float4 v = make_float4(0.f, 0.f, 0.f, 0.f);
            if (row0 + r < n)
                v = *(const float4*)(x + (size_t)(row0 + r) * K + k0 + kq * 4);
            xs[r * 37 + kq * 4 + 0] = v.x;
            xs[r * 37 + kq * 4 + 1] = v.y;
            xs[r * 37 + kq * 4 + 2] = v.z;
            xs[r * 37 + kq * 4 + 3] = v.w;
        }
        __syncthreads();
#pragma unroll 2
        for (int kk = 0; kk < 32; kk++) {
            float4 wlo = *(const float4*)(&Wl[kk * 64 + c0]);
            float4 whi = *(const float4*)(&Wl[kk * 64 + c0 + 4]);
            float xf[8];
#pragma unroll
            for (int i = 0; i < 8; i++) xf[i] = xs[(r0 + i) * 37 + kk];
#pragma unroll
            for (int i = 0; i < 8; i++) {
                acc[i][0] += xf[i] * wlo.x; acc[i][1] += xf[i] * wlo.y;
                acc[i][2] += xf[i] * wlo.z; acc[i][3] += xf[i] * wlo.w;
                acc[i][4] += xf[i] * whi.x; acc[i][5] += xf[i] * whi.y;
                acc[i][6] += xf[i] * whi.z; acc[i][7] += xf[i] * whi.w;
            }
        }
    }
#pragma unroll
    for (int i = 0; i < 8; i++) {
        int row = row0 + r0 + i;
        if (row < n) {
            *(float4*)(&out[(size_t)row * 64 + c0]) =
                make_float4(acc[i][0], acc[i][1], acc[i][2], acc[i][3]);
            *(float4*)(&out[(size_t)row * 64 + c0 + 4]) =
                make_float4(acc[i][4], acc[i][5], acc[i][6], acc[i][7]);
        }
    }
}

// fused GCN aggregate: wave per dst node, lane = feature column, 8-deep ILP.
__global__ __launch_bounds__(256) void k_conv(float* __restrict__ out, const float* __restrict__ h,
                                              const int2* __restrict__ edges,
                                              const int* __restrict__ row,
                                              const float* __restrict__ dinv,
                                              const float* __restrict__ bias, int n) {
    int d = blockIdx.x * 4 + (threadIdx.x >> 6);
    if (d >= n) return;
    int lane = threadIdx.x & 63;
    int a = row[d], b = row[d + 1];
    float acc[8] = {0.f, 0.f, 0.f, 0.f, 0.f, 0.f, 0.f, 0.f};
    for (int base = a; base < b; base += 64) {
        int m = b - base; if (m > 64) m = 64;
        int sv = 0, wv = 0;
        if (base + lane < b) { int2 e = edges[base + lane]; sv = e.x; wv = e.y; }
        int j = 0;
        for (; j + 7 < m; j += 8) {
#pragma unroll
            for (int q = 0; q < 8; q++) {
                int s = __shfl(sv, j + q);
                float w = __int_as_float(__shfl(wv, j + q));
                acc[q] += h[(size_t)s * HID + lane] * w;
            }
        }
        for (; j < m; j++) {
            int s = __shfl(sv, j);
            float w = __int_as_float(__shfl(wv, j));
            acc[0] += h[(size_t)s * HID + lane] * w;
        }
    }
    float di = dinv[d];
    float v = ((acc[0] + acc[1]) + (acc[2] + acc[3])) + ((acc[4] + acc[5]) + (acc[6] + acc[7]))
              + h[(size_t)d * HID + lane] * di * di + bias[lane];
    out[(size_t)d * HID + lane] = v > 0.f ? v : 0.f;
}

// segment-mean pool: wave per segment; counts from rowptr diff.
__global__ __launch_bounds__(256) void k_pool(float* __restrict__ emb, float* __restrict__ esum,
                                              const float* __restrict__ embo,
                                              const float* __restrict__ h,
                                              const int* __restrict__ nodeid,
                                              const int* __restrict__ segrow) {
    int s = blockIdx.x * 4 + (threadIdx.x >> 6);
    if (s >= NSEG) return;
    int lane = threadIdx.x & 63;
    int a = segrow[s], b = segrow[s + 1];
    float ac0 = 0.f, ac1 = 0.f, ac2 = 0.f, ac3 = 0.f;
    for (int base = a; base < b; base += 64) {
        int m = b - base; if (m > 64) m = 64;
        int nid = 0;
        if (base + lane < b) nid = nodeid[base + lane];
        int j = 0;
        for (; j + 3 < m; j += 4) {
            int n0 = __shfl(nid, j),     n1 = __shfl(nid, j + 1);
            int n2 = __shfl(nid, j + 2), n3 = __shfl(nid, j + 3);
            ac0 += h[(size_t)n0 * HID + lane];
            ac1 += h[(size_t)n1 * HID + lane];
            ac2 += h[(size_t)n2 * HID + lane];
            ac3 += h[(size_t)n3 * HID + lane];
        }
        for (; j < m; j++) {
            int n0 = __shfl(nid, j);
            ac0 += h[(size_t)n0 * HID + lane];
        }
    }
    float mean = ((ac0 + ac1) + (ac2 + ac3)) / fmaxf((float)(b - a), 1.0f);
    emb[(size_t)s * HID + lane] = mean;
    if (esum) esum[(size_t)s * HID + lane] = mean + embo[(size_t)s * HID + lane];
}

// ---------------- classifier ----------------

__global__ __launch_bounds__(256) void k_cls(float* __restrict__ hcls,
                                             const float* __restrict__ s,
                                             const float* __restrict__ Wm1) {
    __shared__ float sl[KC * 16];
    int tid = threadIdx.x;
    int k0 = blockIdx.x * KC;
    for (int i = tid; i < KC * 16; i += 256) {
        int kk = i >> 4, b = i & 15;
        sl[i] = s[b * SDIM + k0 + kk];
    }
    __syncthreads();
    int c4 = tid * 4;
    bool active = c4 < CLS;
    const float zero4[4] = {0.f, 0.f, 0.f, 0.f};
    float4 acc[16];
#pragma unroll
    for (int b = 0; b < 16; b++) acc[b] = make_float4(0.f, 0.f, 0.f, 0.f);
    for (int kk = 0; kk < KC; kk++) {
        float4 w = active ? *(const float4*)(&Wm1[(size_t)(k0 + kk) * CLS + c4])
                          : *(const float4*)zero4;
#pragma unroll
        for (int b = 0; b < 16; b++) {
            float sv = sl[kk * 16 + b];
            acc[b].x += sv * w.x; acc[b].y += sv * w.y;
            acc[b].z += sv * w.z; acc[b].w += sv * w.w;
        }
    }
    if (active) {
#pragma unroll
        for (int b = 0; b < 16; b++) {
            unsafeAtomicAdd(&hcls[b * CLS + c4 + 0], acc[b].x);
            unsafeAtomicAdd(&hcls[b * CLS + c4 + 1], acc[b].y);
            unsafeAtomicAdd(&hcls[b * CLS + c4 + 2], acc[b].z);
            unsafeAtomicAdd(&hcls[b * CLS + c4 + 3], acc[b].w);
        }
    }
}

__global__ void k_bn(float* __restrict__ hact, const float* __restrict__ hcls,
                     const float* __restrict__ bm1, const float* __restrict__ gamma,
                     const float* __restrict__ beta, const float* __restrict__ mean,
                     const float* __restrict__ var) {
    int i = blockIdx.x * blockDim.x + threadIdx.x;
    if (i >= BSZ * CLS) return;
    int j = i % CLS;
    float t = hcls[i] + bm1[j];
    t = gamma[j] * (t - mean[j]) * rsqrtf(var[j] + 1e-5f) + beta[j];
    hact[i] = t > 0.f ? t : 0.01f * t;
}

__global__ void k_out(float* __restrict__ outp, const float* __restrict__ hact,
                      const float* __restrict__ Wm2, const float* __restrict__ bm2) {
    int tid = threadIdx.x;              // one block of 256
    int oi = tid >> 3, part = tid & 7;  // 32 outputs x 8 partials
    int b = oi >> 1, o = oi & 1;
    float acc = (part == 0) ? bm2[o] : 0.f;
    for (int k = part; k < CLS; k += 8) acc += hact[b * CLS + k] * Wm2[k * OCH + o];
    unsafeAtomicAdd(&outp[b * OCH + o], acc);
}

extern "C" void kernel_launch(void* const* d_in, const int* in_sizes, int n_in,
                              void* d_out, int out_size, void* d_ws, size_t ws_size,
                              hipStream_t stream) {
    const float* x1  = (const float*)d_in[0];
    const int*   nl  = (const int*)d_in[1];
    const int*   ei1 = (const int*)d_in[2];
    const float* ew1 = (const float*)d_in[3];
    const int*   ba1 = (const int*)d_in[4];
    const float* x2  = (const float*)d_in[5];
    const int*   rl  = (const int*)d_in[6];
    const int*   ei2 = (const int*)d_in[7];
    const float* ew2 = (const float*)d_in[8];
    const int*   ba2 = (const int*)d_in[9];
    const float* W1a = (const float*)d_in[10];
    const float* b1a = (const float*)d_in[11];
    const float* W1b = (const float*)d_in[12];
    const float* b1b = (const float*)d_in[13];
    const float* W2a = (const float*)d_in[14];
    const float* b2a = (const float*)d_in[15];
    const float* W2b = (const float*)d_in[16];
    const float* b2b = (const float*)d_in[17];
    const float* Wm1 = (const float*)d_in[18];
    const float* bm1 = (const float*)d_in[19];
    const float* gam = (const float*)d_in[20];
    const float* bet = (const float*)d_in[21];
    const float* bmn = (const float*)d_in[22];
    const float* bvr = (const float*)d_in[23];
    const float* Wm2 = (const float*)d_in[24];
    const float* bm2 = (const float*)d_in[25];

    float* out  = (float*)d_out;
    float* emb1 = out + 32;               // embedding        (16 x 9472)
    float* emb2 = emb1 + NSEG * HID;      // embedding_roi
    float* esum = emb2 + NSEG * HID;      // embedding + embedding_roi

    // ---- workspace carve ----
    char* p = (char*)d_ws;
    auto carve = [&](size_t nbytes) { char* q = p; p += (nbytes + 255) & ~(size_t)255; return (void*)q; };
    int*   row1    = (int*)  carve((N1 + 1) * 4);
    int2*  edges1  = (int2*) carve((size_t)E1 * 8);
    float* dinv1   = (float*)carve(N1 * 4);
    float* A1      = (float*)carve((size_t)N1 * HID * 4);
    float* B1      = (float*)carve((size_t)N1 * HID * 4);
    int*   nodeid1 = (int*)  carve(N1 * 4);
    int*   segrow1 = (int*)  carve((NSEG + 1) * 4);
    int*   segoff1 = (int*)  carve(NSEG * 4);
    int*   bh      = (int*)  carve((NB1 * BLK1 + 1) * 4);
    int*   obh     = (int*)  carve((NB1 * BLK1 + 1) * 4);
    int*   deg     = (int*)  carve(N1 * 4);
    int*   row2    = (int*)  carve((N2 + 1) * 4);
    int*   off2    = (int*)  carve(N2 * 4);
    int2*  edges2  = (int2*) carve((size_t)E2 * 8);
    float* dinv2   = (float*)carve(N2 * 4);
    float* A2      = (float*)carve((size_t)N2 * HID * 4);
    float* B2      = (float*)carve((size_t)N2 * HID * 4);
    int*   nodeid2 = (int*)  carve(N2 * 4);
    int*   segrow2 = (int*)  carve((NSEG + 1) * 4);
    int*   segoff2 = (int*)  carve(NSEG * 4);
    int*   part    = (int*)  carve(256 * 4);
    float* hcls    = (float*)carve(BSZ * CLS * 4);
    float* hact    = (float*)carve(BSZ * CLS * 4);
    int2*  tmp1    = (int2*)A1;           // 16.8 MB aliases A1 (33.5 MB): CSR build
                                          // completes before A1's first GEMM write

    const int* src1 = ei1;
    const int* dst1 = ei1 + E1;
    const int* src2 = ei2;
    const int* dst2 = ei2 + E2;

    hipMemsetAsync(d_out, 0, (size_t)out_size * sizeof(float), stream);
    hipMemsetAsync(hcls, 0, BSZ * CLS * sizeof(float), stream);

    // ---------------- graph 2 (ROI graph, small; R5 multi-kernel build) ----------------
    hipMemsetAsync(off2, 0, N2 * 4, stream);
    k_hist_dst<<<(E2 + 255) / 256, 256, 0, stream>>>(off2, dst2, E2);
    k_scan_one<<<1, 256, 0, stream>>>(off2, row2, N2);
    hipMemcpyAsync(off2, row2, N2 * 4, hipMemcpyDeviceToDevice, stream);
    k_fill_edges<<<(E2 + 255) / 256, 256, 0, stream>>>(edges2, off2, src2, dst2, ew2, E2);
    k_deg_dinv<<<(N2 + 255) / 256, 256, 0, stream>>>(dinv2, row2, edges2, N2);
    k_scale<<<(N2 + 255) / 256, 256, 0, stream>>>(edges2, row2, dinv2, N2);

    k_gemm<INCH><<<(N2 + 255) / 256, 256, 0, stream>>>(A2, x2, W2a, N2);
    k_conv<<<(N2 + 3) / 4, 256, 0, stream>>>(B2, A2, edges2, row2, dinv2, b2a, N2);
    k_gemm<HID><<<(N2 + 255) / 256, 256, 0, stream>>>(A2, B2, W2b, N2);
    k_conv<<<(N2 + 3) / 4, 256, 0, stream>>>(B2, A2, edges2, row2, dinv2, b2b, N2);
    // graph-2 final features now in B2

    hipMemsetAsync(segoff2, 0, NSEG * 4, stream);
    k_hist_seg<<<(N2 + 255) / 256, 256, 0, stream>>>(segoff2, ba2, rl, N2);
    k_scan_one<<<1, 256, 0, stream>>>(segoff2, segrow2, NSEG);
    hipMemcpyAsync(segoff2, segrow2, NSEG * 4, hipMemcpyDeviceToDevice, stream);
    k_fill_seg<<<(N2 + 255) / 256, 256, 0, stream>>>(nodeid2, segoff2, ba2, rl, N2);
    k_pool<<<(NSEG + 3) / 4, 256, 0, stream>>>(emb2, (float*)nullptr, (const float*)nullptr,
                                               B2, nodeid2, segrow2);

    // ---------------- graph 1: radix-partition CSR build ----------------
    k_p1<<<BLK1, 256, 0, stream>>>(bh, dst1);
    k_scan1<<<(NB1 * BLK1 + 1023) / 1024, 256, 0, stream>>>(bh, obh, part, NB1 * BLK1);
    k_scan2<<<1, 256, 0, stream>>>(part, (NB1 * BLK1 + 1023) / 1024);
    k_scan3<<<(NB1 * BLK1 + 255) / 256, 256, 0, stream>>>(obh, part, NB1 * BLK1, E1);
    k_p2<<<BLK1, 256, 0, stream>>>(tmp1, obh, src1, dst1, ew1);
    k_p3a<<<NB1, 256, 0, stream>>>(deg, dinv1, tmp1, obh);
    k_scan1<<<(N1 + 1023) / 1024, 256, 0, stream>>>(deg, row1, part, N1);
    k_scan2<<<1, 256, 0, stream>>>(part, (N1 + 1023) / 1024);
    k_scan3<<<(N1 + 255) / 256, 256, 0, stream>>>(row1, part, N1, E1);
    k_p3b<<<NB1, 256, 0, stream>>>(edges1, tmp1, obh, row1, dinv1);

    // ---------------- graph 1: convs ----------------
    k_gemm<INCH><<<N1 / 256, 256, 0, stream>>>(A1, x1, W1a, N1);
    k_conv<<<(N1 + 3) / 4, 256, 0, stream>>>(B1, A1, edges1, row1, dinv1, b1a, N1);
    k_gemm<HID><<<N1 / 256, 256, 0, stream>>>(A1, B1, W1b, N1);
    k_conv<<<(N1 + 3) / 4, 256, 0, stream>>>(B1, A1, edges1, row1, dinv1, b1b, N1);

    hipMemsetAsync(segoff1, 0, NSEG * 4, stream);
    k_hist_seg<<<(N1 + 255) / 256, 256, 0, stream>>>(segoff1, ba1, nl, N1);
    k_scan_one<<<1, 256, 0, stream>>>(segoff1, segrow1, NSEG);
    hipMemcpyAsync(segoff1, segrow1, NSEG * 4, hipMemcpyDeviceToDevice, stream);
    k_fill_seg<<<(N1 + 255) / 256, 256, 0, stream>>>(nodeid1, segoff1, ba1, nl, N1);
    k_pool<<<(NSEG + 3) / 4, 256, 0, stream>>>(emb1, esum, emb2, B1, nodeid1, segrow1);

    // ---------------- classifier ----------------
    k_cls<<<SDIM / KC, 256, 0, stream>>>(hcls, esum, Wm1);
    k_bn<<<(BSZ * CLS + 255) / 256, 256, 0, stream>>>(hact, hcls, bm1, gam, bet, bmn, bvr);
    k_out<<<1, 256, 0, stream>>>(out, hact, Wm2, bm2);
}

// Round 8
// 773.219 us; speedup vs baseline: 1.5530x; 1.0209x over previous
//
#include <hip/hip_runtime.h>
#include <hip/hip_bf16.h>

#define N1 131072
#define E1 2097152
#define N2 2368
#define E2 37888
#define NROIS 148
#define BSZ 16
#define HID 64
#define INCH 128
#define NSEG (BSZ*NROIS)      /* 2368 */
#define SDIM (NROIS*HID)      /* 9472 */
#define CLS 1000
#define OCH 2

#define KT1 74                /* k tiles for k_cls */
#define KCC 128               /* k per tile (74*128 = 9472) */
#define CT1 4                 /* col tiles of 256 */

#define NB1 512               /* dst buckets for graph-1 partition */
#define BLK1 512              /* partition blocks */
#define EPB (E1/BLK1)         /* 4096 edges per block */
#define NPB (N1/NB1)          /* 256 nodes per bucket */

// ---------------- generic small-graph CSR build ----------------

__global__ void k_hist_dst(int* __restrict__ cnt, const int* __restrict__ dst, int E) {
    int e = blockIdx.x * 256 + threadIdx.x;
    if (e < E) atomicAdd(&cnt[dst[e]], 1);
}

__global__ void k_hist_seg(int* __restrict__ cnt, const int* __restrict__ batch,
                           const int* __restrict__ label, int n) {
    int i = blockIdx.x * 256 + threadIdx.x;
    if (i < n) atomicAdd(&cnt[batch[i] * NROIS + label[i]], 1);
}

// multi-block exclusive scan
__global__ void k_scan1(const int* __restrict__ in, int* __restrict__ out,
                        int* __restrict__ part, int n) {
    __shared__ int sh[256];
    int t = threadIdx.x;
    int i0 = blockIdx.x * 1024 + t * 4;
    int v0 = (i0     < n) ? in[i0]     : 0;
    int v1 = (i0 + 1 < n) ? in[i0 + 1] : 0;
    int v2 = (i0 + 2 < n) ? in[i0 + 2] : 0;
    int v3 = (i0 + 3 < n) ? in[i0 + 3] : 0;
    int tot = v0 + v1 + v2 + v3;
    sh[t] = tot; __syncthreads();
    for (int off = 1; off < 256; off <<= 1) {
        int x = 0; if (t >= off) x = sh[t - off];
        __syncthreads();
        if (t >= off) sh[t] += x;
        __syncthreads();
    }
    int excl = sh[t] - tot;
    if (t == 255) part[blockIdx.x] = sh[255];
    if (i0     < n) out[i0]     = excl;
    if (i0 + 1 < n) out[i0 + 1] = excl + v0;
    if (i0 + 2 < n) out[i0 + 2] = excl + v0 + v1;
    if (i0 + 3 < n) out[i0 + 3] = excl + v0 + v1 + v2;
}

__global__ void k_scan2(int* __restrict__ part, int cnt) {
    __shared__ int sh[256];
    int t = threadIdx.x;
    int v = (t < cnt) ? part[t] : 0;
    sh[t] = v; __syncthreads();
    for (int off = 1; off < 256; off <<= 1) {
        int x = 0; if (t >= off) x = sh[t - off];
        __syncthreads();
        if (t >= off) sh[t] += x;
        __syncthreads();
    }
    if (t < cnt) part[t] = sh[t] - v;
}

__global__ void k_scan3(int* __restrict__ out, const int* __restrict__ part, int n, int total) {
    int i = blockIdx.x * 256 + threadIdx.x;
    if (i < n) out[i] += part[i >> 10];
    if (i == 0) out[n] = total;
}

// single-block exclusive scan for small arrays; writes sentinel out[n]
__global__ void k_scan_one(const int* __restrict__ in, int* __restrict__ out, int n) {
    __shared__ int sh[256];
    __shared__ int carry;
    int t = threadIdx.x;
    if (t == 0) carry = 0;
    __syncthreads();
    for (int base = 0; base < n; base += 256) {
        int i = base + t;
        int v = (i < n) ? in[i] : 0;
        sh[t] = v; __syncthreads();
        for (int off = 1; off < 256; off <<= 1) {
            int x = 0; if (t >= off) x = sh[t - off];
            __syncthreads();
            if (t >= off) sh[t] += x;
            __syncthreads();
        }
        if (i < n) out[i] = carry + sh[t] - v;
        __syncthreads();
        if (t == 255) carry += sh[255];
        __syncthreads();
    }
    if (t == 0) out[n] = carry;
}

__global__ void k_fill_edges(int2* __restrict__ edges, int* __restrict__ off,
                             const int* __restrict__ src, const int* __restrict__ dst,
                             const float* __restrict__ ew, int E) {
    int e = blockIdx.x * 256 + threadIdx.x;
    if (e >= E) return;
    int pos = atomicAdd(&off[dst[e]], 1);
    edges[pos] = make_int2(src[e], __float_as_int(ew[e]));
}

__global__ void k_fill_seg(int* __restrict__ nodeid, int* __restrict__ off,
                           const int* __restrict__ batch, const int* __restrict__ label, int n) {
    int i = blockIdx.x * 256 + threadIdx.x;
    if (i >= n) return;
    int pos = atomicAdd(&off[batch[i] * NROIS + label[i]], 1);
    nodeid[pos] = i;
}

__global__ void k_deg_dinv(float* __restrict__ dinv, const int* __restrict__ row,
                           const int2* __restrict__ edges, int n) {
    int d = blockIdx.x * 256 + threadIdx.x;
    if (d >= n) return;
    int a = row[d], b = row[d + 1];
    float s = 1.0f;
    for (int i = a; i < b; i++) s += __int_as_float(edges[i].y);
    dinv[d] = rsqrtf(s);
}

__global__ void k_scale(int2* __restrict__ edges, const int* __restrict__ row,
                        const float* __restrict__ dinv, int n) {
    int d = blockIdx.x * 256 + threadIdx.x;
    if (d >= n) return;
    int a = row[d], b = row[d + 1];
    float dd = dinv[d];
    for (int i = a; i < b; i++) {
        int2 e = edges[i];
        edges[i].y = __float_as_int(dinv[e.x] * __int_as_float(e.y) * dd);
    }
}

// ---------------- graph-1 radix-partition CSR build ----------------

// P1: per-block histogram of 512 dst-buckets over its 4096-edge chunk.
__global__ __launch_bounds__(256) void k_p1(int* __restrict__ bh, const int* __restrict__ dst) {
    __shared__ int cnt[NB1];
    int t = threadIdx.x, blk = blockIdx.x;
    for (int i = t; i < NB1; i += 256) cnt[i] = 0;
    __syncthreads();
    int base = blk * EPB;
    for (int i = t; i < EPB; i += 256) atomicAdd(&cnt[dst[base + i] >> 8], 1);
    __syncthreads();
    for (int b = t; b < NB1; b += 256) bh[b * BLK1 + blk] = cnt[b];   // bucket-major
}

// P2: partition edges into bucket-contiguous, block-exclusive tmp regions.
// pack = src (17 bits) | dst_local (8 bits) << 17
__global__ __launch_bounds__(256) void k_p2(int2* __restrict__ tmp, const int* __restrict__ obh,
                                            const int* __restrict__ src,
                                            const int* __restrict__ dst,
                                            const float* __restrict__ ew) {
    __shared__ int cur[NB1];
    int t = threadIdx.x, blk = blockIdx.x;
    for (int b = t; b < NB1; b += 256) cur[b] = obh[b * BLK1 + blk];
    __syncthreads();
    int base = blk * EPB;
    for (int i = t; i < EPB; i += 256) {
        int e = base + i;
        int d = dst[e];
        int pos = atomicAdd(&cur[d >> 8], 1);
        tmp[pos] = make_int2(src[e] | ((d & 255) << 17), __float_as_int(ew[e]));
    }
}

// P3a: per-bucket node histogram + edge-weight sums -> deg, dinv.
__global__ __launch_bounds__(256) void k_p3a(int* __restrict__ deg, float* __restrict__ dinv,
                                             const int2* __restrict__ tmp,
                                             const int* __restrict__ obh) {
    __shared__ int h[NPB];
    __shared__ float ws[NPB];
    int t = threadIdx.x, b = blockIdx.x;
    for (int i = t; i < NPB; i += 256) { h[i] = 0; ws[i] = 0.f; }
    __syncthreads();
    int a  = obh[b * BLK1];
    int e_ = (b == NB1 - 1) ? E1 : obh[(b + 1) * BLK1];
    for (int i = a + t; i < e_; i += 256) {
        int2 ed = tmp[i];
        int dl = (ed.x >> 17) & 255;
        atomicAdd(&h[dl], 1);
        atomicAdd(&ws[dl], __int_as_float(ed.y));
    }
    __syncthreads();
    for (int i = t; i < NPB; i += 256) {
        deg[b * NPB + i] = h[i];
        dinv[b * NPB + i] = rsqrtf(1.f + ws[i]);
    }
}

// P3b: final CSR placement (LDS cursors, block-exclusive window) + normalize.
__global__ __launch_bounds__(256) void k_p3b(int2* __restrict__ edges,
                                             const int2* __restrict__ tmp,
                                             const int* __restrict__ obh,
                                             const int* __restrict__ row,
                                             const float* __restrict__ dinv) {
    __shared__ int cur[NPB];
    __shared__ float dvl[NPB];
    int t = threadIdx.x, b = blockIdx.x;
    int n0 = b * NPB;
    for (int i = t; i < NPB; i += 256) {
        cur[i] = row[n0 + i];
        dvl[i] = dinv[n0 + i];
    }
    __syncthreads();
    int a  = obh[b * BLK1];
    int e_ = (b == NB1 - 1) ? E1 : obh[(b + 1) * BLK1];
    for (int i = a + t; i < e_; i += 256) {
        int2 ed = tmp[i];
        int dl = (ed.x >> 17) & 255;
        int s = ed.x & 0x1FFFF;
        int pos = atomicAdd(&cur[dl], 1);
        float w = dinv[s] * __int_as_float(ed.y) * dvl[dl];
        edges[pos] = make_int2(s, __float_as_int(w));
    }
}

// ---------------- dense ops ----------------

// out[n][64] = x[n][K] @ W[K][64]. Block: 256 rows x 64 cols; thread tile 8x8.
template <int K>
__global__ __launch_bounds__(256) void k_gemm(float* __restrict__ out,
                                              const float* __restrict__ x,
                                              const float* __restrict__ W, int n) {
    __shared__ float Wl[32 * 64];       // [kk][col]
    __shared__ float xs[256 * 37];      // [r][kk], stride 37
    int tid = threadIdx.x;
    int row0 = blockIdx.x * 256;
    int r0 = (tid >> 3) * 8;
    int c0 = (tid & 7) * 8;
    float acc[8][8];
#pragma unroll
    for (int i = 0; i < 8; i++)
#pragma unroll
        for (int j = 0; j < 8; j++) acc[i][j] = 0.f;

    for (int k0 = 0; k0 < K; k0 += 32) {
        __syncthreads();
        {
            const float4* W4 = (const float4*)(W + k0 * 64);
            float4* Wl4 = (float4*)Wl;
#pragma unroll
            for (int i = 0; i < 2; i++) Wl4[tid + i * 256] = W4[tid + i * 256];
        }
#pragma unroll
        for (int i = 0; i < 8; i++) {
            int idx = tid + i * 256;
            int r = idx >> 3, kq = idx & 7;
            float4 v = make_float4(0.f, 0.f, 0.f, 0.f);
            if (row0 + r < n)
                v = *(const float4*)(x + (size_t)(row0 + r) * K + k0 + kq * 4);
            xs[r * 37 + kq * 4 + 0] = v.x;
            xs[r * 37 + kq * 4 + 1] = v.y;
            xs[r * 37 + kq * 4 + 2] = v.z;
            xs[r * 37 + kq * 4 + 3] = v.w;
        }
        __syncthreads();
#pragma unroll 2
        for (int kk = 0; kk < 32; kk++) {
            float4 wlo = *(const float4*)(&Wl[kk * 64 + c0]);
            float4 whi = *(const float4*)(&Wl[kk * 64 + c0 + 4]);
            float xf[8];
#pragma unroll
            for (int i = 0; i < 8; i++) xf[i] = xs[(r0 + i) * 37 + kk];
#pragma unroll
            for (int i = 0; i < 8; i++) {
                acc[i][0] += xf[i] * wlo.x; acc[i][1] += xf[i] * wlo.y;
                acc[i][2] += xf[i] * wlo.z; acc[i][3] += xf[i] * wlo.w;
                acc[i][4] += xf[i] * whi.x; acc[i][5] += xf[i] * whi.y;
                acc[i][6] += xf[i] * whi.z; acc[i][7] += xf[i] * whi.w;
            }
        }
    }
#pragma unroll
    for (int i = 0; i < 8; i++) {
        int row = row0 + r0 + i;
        if (row < n) {
            *(float4*)(&out[(size_t)row * 64 + c0]) =
                make_float4(acc[i][0], acc[i][1], acc[i][2], acc[i][3]);
            *(float4*)(&out[(size_t)row * 64 + c0 + 4]) =
                make_float4(acc[i][4], acc[i][5], acc[i][6], acc[i][7]);
        }
    }
}

// fused GCN aggregate: wave per dst node, lane = feature column, 8-deep ILP.
__global__ __launch_bounds__(256) void k_conv(float* __restrict__ out, const float* __restrict__ h,
                                              const int2* __restrict__ edges,
                                              const int* __restrict__ row,
                                              const float* __restrict__ dinv,
                                              const float* __restrict__ bias, int n) {
    int d = blockIdx.x * 4 + (threadIdx.x >> 6);
    if (d >= n) return;
    int lane = threadIdx.x & 63;
    int a = row[d], b = row[d + 1];
    float acc[8] = {0.f, 0.f, 0.f, 0.f, 0.f, 0.f, 0.f, 0.f};
    for (int base = a; base < b; base += 64) {
        int m = b - base; if (m > 64) m = 64;
        int sv = 0, wv = 0;
        if (base + lane < b) { int2 e = edges[base + lane]; sv = e.x; wv = e.y; }
        int j = 0;
        for (; j + 7 < m; j += 8) {
#pragma unroll
            for (int q = 0; q < 8; q++) {
                int s = __shfl(sv, j + q);
                float w = __int_as_float(__shfl(wv, j + q));
                acc[q] += h[(size_t)s * HID + lane] * w;
            }
        }
        for (; j < m; j++) {
            int s = __shfl(sv, j);
            float w = __int_as_float(__shfl(wv, j));
            acc[0] += h[(size_t)s * HID + lane] * w;
        }
    }
    float di = dinv[d];
    float v = ((acc[0] + acc[1]) + (acc[2] + acc[3])) + ((acc[4] + acc[5]) + (acc[6] + acc[7]))
              + h[(size_t)d * HID + lane] * di * di + bias[lane];
    out[(size_t)d * HID + lane] = v > 0.f ? v : 0.f;
}

// segment-mean pool: wave per segment; counts from rowptr diff.
__global__ __launch_bounds__(256) void k_pool(float* __restrict__ emb, float* __restrict__ esum,
                                              const float* __restrict__ embo,
                                              const float* __restrict__ h,
                                              const int* __restrict__ nodeid,
                                              const int* __restrict__ segrow) {
    int s = blockIdx.x * 4 + (threadIdx.x >> 6);
    if (s >= NSEG) return;
    int lane = threadIdx.x & 63;
    int a = segrow[s], b = segrow[s + 1];
    float ac0 = 0.f, ac1 = 0.f, ac2 = 0.f, ac3 = 0.f;
    for (int base = a; base < b; base += 64) {
        int m = b - base; if (m > 64) m = 64;
        int nid = 0;
        if (base + lane < b) nid = nodeid[base + lane];
        int j = 0;
        for (; j + 3 < m; j += 4) {
            int n0 = __shfl(nid, j),     n1 = __shfl(nid, j + 1);
            int n2 = __shfl(nid, j + 2), n3 = __shfl(nid, j + 3);
            ac0 += h[(size_t)n0 * HID + lane];
            ac1 += h[(size_t)n1 * HID + lane];
            ac2 += h[(size_t)n2 * HID + lane];
            ac3 += h[(size_t)n3 * HID + lane];
        }
        for (; j < m; j++) {
            int n0 = __shfl(nid, j);
            ac0 += h[(size_t)n0 * HID + lane];
        }
    }
    float mean = ((ac0 + ac1) + (ac2 + ac3)) / fmaxf((float)(b - a), 1.0f);
    emb[(size_t)s * HID + lane] = mean;
    if (esum) esum[(size_t)s * HID + lane] = mean + embo[(size_t)s * HID + lane];
}

// ---------------- classifier ----------------

// Partial GEMV: block (kt, ct) computes part[kt][ct][16][256] over k-chunk kt
// for cols [ct*256, ct*256+256). No global atomics: block-exclusive slab.
__global__ __launch_bounds__(256) void k_cls(float* __restrict__ part_,
                                             const float* __restrict__ s,
                                             const float* __restrict__ Wm1) {
    __shared__ float sl[KCC * 16];      // [kk][b]
    int tid = threadIdx.x;
    int kt = blockIdx.x >> 2, ct = blockIdx.x & 3;
    int k0 = kt * KCC;
    for (int i = tid; i < KCC * 16; i += 256) {
        int kk = i & (KCC - 1), b = i >> 7;        // coalesced over kk
        sl[kk * 16 + b] = s[b * SDIM + k0 + kk];
    }
    __syncthreads();
    int c = ct * 256 + tid;
    bool active = c < CLS;
    float acc[16];
#pragma unroll
    for (int b = 0; b < 16; b++) acc[b] = 0.f;
    const float* wp = Wm1 + (size_t)k0 * CLS + c;
#pragma unroll 2
    for (int kk = 0; kk < KCC; kk++) {
        float w = active ? wp[(size_t)kk * CLS] : 0.f;
        float4 s0 = *(const float4*)(&sl[kk * 16 + 0]);
        float4 s1 = *(const float4*)(&sl[kk * 16 + 4]);
        float4 s2 = *(const float4*)(&sl[kk * 16 + 8]);
        float4 s3 = *(const float4*)(&sl[kk * 16 + 12]);
        acc[0]  += s0.x * w; acc[1]  += s0.y * w; acc[2]  += s0.z * w; acc[3]  += s0.w * w;
        acc[4]  += s1.x * w; acc[5]  += s1.y * w; acc[6]  += s1.z * w; acc[7]  += s1.w * w;
        acc[8]  += s2.x * w; acc[9]  += s2.y * w; acc[10] += s2.z * w; acc[11] += s2.w * w;
        acc[12] += s3.x * w; acc[13] += s3.y * w; acc[14] += s3.z * w; acc[15] += s3.w * w;
    }
    float* pp = part_ + (size_t)(kt * CT1 + ct) * 16 * 256;
#pragma unroll
    for (int b = 0; b < 16; b++) pp[b * 256 + tid] = acc[b];
}

// reduce partials: hcls[b][c] = sum_kt part[kt][ct(c)][b][c&255]
__global__ void k_cred(float* __restrict__ hcls, const float* __restrict__ part_) {
    int idx = blockIdx.x * 256 + threadIdx.x;
    if (idx >= BSZ * CLS) return;
    int b = idx / CLS, c = idx % CLS;
    int ct = c >> 8, cl = c & 255;
    float sum = 0.f;
#pragma unroll 2
    for (int kt = 0; kt < KT1; kt++)
        sum += part_[((size_t)(kt * CT1 + ct) * 16 + b) * 256 + cl];
    hcls[idx] = sum;
}

__global__ void k_bn(float* __restrict__ hact, const float* __restrict__ hcls,
                     const float* __restrict__ bm1, const float* __restrict__ gamma,
                     const float* __restrict__ beta, const float* __restrict__ mean,
                     const float* __restrict__ var) {
    int i = blockIdx.x * blockDim.x + threadIdx.x;
    if (i >= BSZ * CLS) return;
    int j = i % CLS;
    float t = hcls[i] + bm1[j];
    t = gamma[j] * (t - mean[j]) * rsqrtf(var[j] + 1e-5f) + beta[j];
    hact[i] = t > 0.f ? t : 0.01f * t;
}

__global__ void k_out(float* __restrict__ outp, const float* __restrict__ hact,
                      const float* __restrict__ Wm2, const float* __restrict__ bm2) {
    int tid = threadIdx.x;              // one block of 256
    int oi = tid >> 3, part = tid & 7;  // 32 outputs x 8 partials
    int b = oi >> 1, o = oi & 1;
    float acc = (part == 0) ? bm2[o] : 0.f;
    for (int k = part; k < CLS; k += 8) acc += hact[b * CLS + k] * Wm2[k * OCH + o];
    unsafeAtomicAdd(&outp[b * OCH + o], acc);
}

extern "C" void kernel_launch(void* const* d_in, const int* in_sizes, int n_in,
                              void* d_out, int out_size, void* d_ws, size_t ws_size,
                              hipStream_t stream) {
    const float* x1  = (const float*)d_in[0];
    const int*   nl  = (const int*)d_in[1];
    const int*   ei1 = (const int*)d_in[2];
    const float* ew1 = (const float*)d_in[3];
    const int*   ba1 = (const int*)d_in[4];
    const float* x2  = (const float*)d_in[5];
    const int*   rl  = (const int*)d_in[6];
    const int*   ei2 = (const int*)d_in[7];
    const float* ew2 = (const float*)d_in[8];
    const int*   ba2 = (const int*)d_in[9];
    const float* W1a = (const float*)d_in[10];
    const float* b1a = (const float*)d_in[11];
    const float* W1b = (const float*)d_in[12];
    const float* b1b = (const float*)d_in[13];
    const float* W2a = (const float*)d_in[14];
    const float* b2a = (const float*)d_in[15];
    const float* W2b = (const float*)d_in[16];
    const float* b2b = (const float*)d_in[17];
    const float* Wm1 = (const float*)d_in[18];
    const float* bm1 = (const float*)d_in[19];
    const float* gam = (const float*)d_in[20];
    const float* bet = (const float*)d_in[21];
    const float* bmn = (const float*)d_in[22];
    const float* bvr = (const float*)d_in[23];
    const float* Wm2 = (const float*)d_in[24];
    const float* bm2 = (const float*)d_in[25];

    float* out  = (float*)d_out;
    float* emb1 = out + 32;               // embedding        (16 x 9472)
    float* emb2 = emb1 + NSEG * HID;      // embedding_roi
    float* esum = emb2 + NSEG * HID;      // embedding + embedding_roi

    // ---- workspace carve ----
    char* p = (char*)d_ws;
    auto carve = [&](size_t nbytes) { char* q = p; p += (nbytes + 255) & ~(size_t)255; return (void*)q; };
    int*   row1    = (int*)  carve((N1 + 1) * 4);
    int2*  edges1  = (int2*) carve((size_t)E1 * 8);
    float* dinv1   = (float*)carve(N1 * 4);
    float* A1      = (float*)carve((size_t)N1 * HID * 4);
    float* B1      = (float*)carve((size_t)N1 * HID * 4);
    int*   nodeid1 = (int*)  carve(N1 * 4);
    int*   segrow1 = (int*)  carve((NSEG + 1) * 4);
    int*   segoff1 = (int*)  carve(NSEG * 4);
    int*   bh      = (int*)  carve((NB1 * BLK1 + 1) * 4);
    int*   obh     = (int*)  carve((NB1 * BLK1 + 1) * 4);
    int*   deg     = (int*)  carve(N1 * 4);
    int*   row2    = (int*)  carve((N2 + 1) * 4);
    int*   off2    = (int*)  carve(N2 * 4);
    int2*  edges2  = (int2*) carve((size_t)E2 * 8);
    float* dinv2   = (float*)carve(N2 * 4);
    float* A2      = (float*)carve((size_t)N2 * HID * 4);
    float* B2      = (float*)carve((size_t)N2 * HID * 4);
    int*   nodeid2 = (int*)  carve(N2 * 4);
    int*   segrow2 = (int*)  carve((NSEG + 1) * 4);
    int*   segoff2 = (int*)  carve(NSEG * 4);
    int*   part    = (int*)  carve(256 * 4);
    float* hcls    = (float*)carve(BSZ * CLS * 4);
    float* hact    = (float*)carve(BSZ * CLS * 4);
    int2*  tmp1    = (int2*)A1;           // 16.8 MB aliases A1: CSR build done
                                          // before A1's first GEMM write
    float* clsp    = B1;                  // 4.85 MB partial slabs alias B1: B1 is
                                          // dead after the last k_pool reads it

    const int* src1 = ei1;
    const int* dst1 = ei1 + E1;
    const int* src2 = ei2;
    const int* dst2 = ei2 + E2;

    hipMemsetAsync(d_out, 0, (size_t)out_size * sizeof(float), stream);

    // ---------------- graph 2 (ROI graph, small) ----------------
    hipMemsetAsync(off2, 0, N2 * 4, stream);
    k_hist_dst<<<(E2 + 255) / 256, 256, 0, stream>>>(off2, dst2, E2);
    k_scan_one<<<1, 256, 0, stream>>>(off2, row2, N2);
    hipMemcpyAsync(off2, row2, N2 * 4, hipMemcpyDeviceToDevice, stream);
    k_fill_edges<<<(E2 + 255) / 256, 256, 0, stream>>>(edges2, off2, src2, dst2, ew2, E2);
    k_deg_dinv<<<(N2 + 255) / 256, 256, 0, stream>>>(dinv2, row2, edges2, N2);
    k_scale<<<(N2 + 255) / 256, 256, 0, stream>>>(edges2, row2, dinv2, N2);

    k_gemm<INCH><<<(N2 + 255) / 256, 256, 0, stream>>>(A2, x2, W2a, N2);
    k_conv<<<(N2 + 3) / 4, 256, 0, stream>>>(B2, A2, edges2, row2, dinv2, b2a, N2);
    k_gemm<HID><<<(N2 + 255) / 256, 256, 0, stream>>>(A2, B2, W2b, N2);
    k_conv<<<(N2 + 3) / 4, 256, 0, stream>>>(B2, A2, edges2, row2, dinv2, b2b, N2);
    // graph-2 final features now in B2

    hipMemsetAsync(segoff2, 0, NSEG * 4, stream);
    k_hist_seg<<<(N2 + 255) / 256, 256, 0, stream>>>(segoff2, ba2, rl, N2);
    k_scan_one<<<1, 256, 0, stream>>>(segoff2, segrow2, NSEG);
    hipMemcpyAsync(segoff2, segrow2, NSEG * 4, hipMemcpyDeviceToDevice, stream);
    k_fill_seg<<<(N2 + 255) / 256, 256, 0, stream>>>(nodeid2, segoff2, ba2, rl, N2);
    k_pool<<<(NSEG + 3) / 4, 256, 0, stream>>>(emb2, (float*)nullptr, (const float*)nullptr,
                                               B2, nodeid2, segrow2);

    // ---------------- graph 1: radix-partition CSR build ----------------
    k_p1<<<BLK1, 256, 0, stream>>>(bh, dst1);
    k_scan1<<<(NB1 * BLK1 + 1023) / 1024, 256, 0, stream>>>(bh, obh, part, NB1 * BLK1);
    k_scan2<<<1, 256, 0, stream>>>(part, (NB1 * BLK1 + 1023) / 1024);
    k_scan3<<<(NB1 * BLK1 + 255) / 256, 256, 0, stream>>>(obh, part, NB1 * BLK1, E1);
    k_p2<<<BLK1, 256, 0, stream>>>(tmp1, obh, src1, dst1, ew1);
    k_p3a<<<NB1, 256, 0, stream>>>(deg, dinv1, tmp1, obh);
    k_scan1<<<(N1 + 1023) / 1024, 256, 0, stream>>>(deg, row1, part, N1);
    k_scan2<<<1, 256, 0, stream>>>(part, (N1 + 1023) / 1024);
    k_scan3<<<(N1 + 255) / 256, 256, 0, stream>>>(row1, part, N1, E1);
    k_p3b<<<NB1, 256, 0, stream>>>(edges1, tmp1, obh, row1, dinv1);

    // ---------------- graph 1: convs ----------------
    k_gemm<INCH><<<N1 / 256, 256, 0, stream>>>(A1, x1, W1a, N1);
    k_conv<<<(N1 + 3) / 4, 256, 0, stream>>>(B1, A1, edges1, row1, dinv1, b1a, N1);
    k_gemm<HID><<<N1 / 256, 256, 0, stream>>>(A1, B1, W1b, N1);
    k_conv<<<(N1 + 3) / 4, 256, 0, stream>>>(B1, A1, edges1, row1, dinv1, b1b, N1);

    hipMemsetAsync(segoff1, 0, NSEG * 4, stream);
    k_hist_seg<<<(N1 + 255) / 256, 256, 0, stream>>>(segoff1, ba1, nl, N1);
    k_scan_one<<<1, 256, 0, stream>>>(segoff1, segrow1, NSEG);
    hipMemcpyAsync(segoff1, segrow1, NSEG * 4, hipMemcpyDeviceToDevice, stream);
    k_fill_seg<<<(N1 + 255) / 256, 256, 0, stream>>>(nodeid1, segoff1, ba1, nl, N1);
    k_pool<<<(NSEG + 3) / 4, 256, 0, stream>>>(emb1, esum, emb2, B1, nodeid1, segrow1);
    // B1 dead from here; clsp aliases it

    // ---------------- classifier ----------------
    k_cls<<<KT1 * CT1, 256, 0, stream>>>(clsp, esum, Wm1);
    k_cred<<<(BSZ * CLS + 255) / 256, 256, 0, stream>>>(hcls, clsp);
    k_bn<<<(BSZ * CLS + 255) / 256, 256, 0, stream>>>(hact, hcls, bm1, gam, bet, bmn, bvr);
    k_out<<<1, 256, 0, stream>>>(out, hact, Wm2, bm2);
}

// Round 9
// 743.551 us; speedup vs baseline: 1.6149x; 1.0399x over previous
//
#include <hip/hip_runtime.h>
#include <hip/hip_bf16.h>

#define N1 131072
#define E1 2097152
#define N2 2368
#define E2 37888
#define NROIS 148
#define BSZ 16
#define HID 64
#define INCH 128
#define NSEG (BSZ*NROIS)      /* 2368 */
#define SDIM (NROIS*HID)      /* 9472 */
#define CLS 1000
#define OCH 2

#define KT1 74                /* k tiles for k_cls */
#define KCC 128               /* k per tile (74*128 = 9472) */
#define CT1 4                 /* col tiles of 256 */

#define NB1 512               /* dst buckets for graph-1 partition */
#define BLK1 512              /* partition blocks */
#define EPB (E1/BLK1)         /* 4096 edges per block */
#define NPB (N1/NB1)          /* 256 nodes per bucket */

__device__ __forceinline__ float bf2f(unsigned short u) {
    union { unsigned int i; float f; } v; v.i = ((unsigned int)u) << 16; return v.f;
}
__device__ __forceinline__ unsigned short f2bf(float f) {
    union { float f; unsigned int i; } v; v.f = f;
    unsigned int r = v.i + 0x7FFF + ((v.i >> 16) & 1);   // round-to-nearest-even
    return (unsigned short)(r >> 16);
}

// ---------------- generic small-graph CSR build ----------------

__global__ void k_hist_dst(int* __restrict__ cnt, const int* __restrict__ dst, int E) {
    int e = blockIdx.x * 256 + threadIdx.x;
    if (e < E) atomicAdd(&cnt[dst[e]], 1);
}

__global__ void k_hist_seg(int* __restrict__ cnt, const int* __restrict__ batch,
                           const int* __restrict__ label, int n) {
    int i = blockIdx.x * 256 + threadIdx.x;
    if (i < n) atomicAdd(&cnt[batch[i] * NROIS + label[i]], 1);
}

// multi-block exclusive scan
__global__ void k_scan1(const int* __restrict__ in, int* __restrict__ out,
                        int* __restrict__ part, int n) {
    __shared__ int sh[256];
    int t = threadIdx.x;
    int i0 = blockIdx.x * 1024 + t * 4;
    int v0 = (i0     < n) ? in[i0]     : 0;
    int v1 = (i0 + 1 < n) ? in[i0 + 1] : 0;
    int v2 = (i0 + 2 < n) ? in[i0 + 2] : 0;
    int v3 = (i0 + 3 < n) ? in[i0 + 3] : 0;
    int tot = v0 + v1 + v2 + v3;
    sh[t] = tot; __syncthreads();
    for (int off = 1; off < 256; off <<= 1) {
        int x = 0; if (t >= off) x = sh[t - off];
        __syncthreads();
        if (t >= off) sh[t] += x;
        __syncthreads();
    }
    int excl = sh[t] - tot;
    if (t == 255) part[blockIdx.x] = sh[255];
    if (i0     < n) out[i0]     = excl;
    if (i0 + 1 < n) out[i0 + 1] = excl + v0;
    if (i0 + 2 < n) out[i0 + 2] = excl + v0 + v1;
    if (i0 + 3 < n) out[i0 + 3] = excl + v0 + v1 + v2;
}

__global__ void k_scan2(int* __restrict__ part, int cnt) {
    __shared__ int sh[256];
    int t = threadIdx.x;
    int v = (t < cnt) ? part[t] : 0;
    sh[t] = v; __syncthreads();
    for (int off = 1; off < 256; off <<= 1) {
        int x = 0; if (t >= off) x = sh[t - off];
        __syncthreads();
        if (t >= off) sh[t] += x;
        __syncthreads();
    }
    if (t < cnt) part[t] = sh[t] - v;
}

__global__ void k_scan3(int* __restrict__ out, const int* __restrict__ part, int n, int total) {
    int i = blockIdx.x * 256 + threadIdx.x;
    if (i < n) out[i] += part[i >> 10];
    if (i == 0) out[n] = total;
}

// single-block exclusive scan for small arrays; writes sentinel out[n]
__global__ void k_scan_one(const int* __restrict__ in, int* __restrict__ out, int n) {
    __shared__ int sh[256];
    __shared__ int carry;
    int t = threadIdx.x;
    if (t == 0) carry = 0;
    __syncthreads();
    for (int base = 0; base < n; base += 256) {
        int i = base + t;
        int v = (i < n) ? in[i] : 0;
        sh[t] = v; __syncthreads();
        for (int off = 1; off < 256; off <<= 1) {
            int x = 0; if (t >= off) x = sh[t - off];
            __syncthreads();
            if (t >= off) sh[t] += x;
            __syncthreads();
        }
        if (i < n) out[i] = carry + sh[t] - v;
        __syncthreads();
        if (t == 255) carry += sh[255];
        __syncthreads();
    }
    if (t == 0) out[n] = carry;
}

__global__ void k_fill_edges(int2* __restrict__ edges, int* __restrict__ off,
                             const int* __restrict__ src, const int* __restrict__ dst,
                             const float* __restrict__ ew, int E) {
    int e = blockIdx.x * 256 + threadIdx.x;
    if (e >= E) return;
    int pos = atomicAdd(&off[dst[e]], 1);
    edges[pos] = make_int2(src[e], __float_as_int(ew[e]));
}

__global__ void k_fill_seg(int* __restrict__ nodeid, int* __restrict__ off,
                           const int* __restrict__ batch, const int* __restrict__ label, int n) {
    int i = blockIdx.x * 256 + threadIdx.x;
    if (i >= n) return;
    int pos = atomicAdd(&off[batch[i] * NROIS + label[i]], 1);
    nodeid[pos] = i;
}

__global__ void k_deg_dinv(float* __restrict__ dinv, const int* __restrict__ row,
                           const int2* __restrict__ edges, int n) {
    int d = blockIdx.x * 256 + threadIdx.x;
    if (d >= n) return;
    int a = row[d], b = row[d + 1];
    float s = 1.0f;
    for (int i = a; i < b; i++) s += __int_as_float(edges[i].y);
    dinv[d] = rsqrtf(s);
}

__global__ void k_scale(int2* __restrict__ edges, const int* __restrict__ row,
                        const float* __restrict__ dinv, int n) {
    int d = blockIdx.x * 256 + threadIdx.x;
    if (d >= n) return;
    int a = row[d], b = row[d + 1];
    float dd = dinv[d];
    for (int i = a; i < b; i++) {
        int2 e = edges[i];
        edges[i].y = __float_as_int(dinv[e.x] * __int_as_float(e.y) * dd);
    }
}

// ---------------- graph-1 radix-partition CSR build ----------------

__global__ __launch_bounds__(256) void k_p1(int* __restrict__ bh, const int* __restrict__ dst) {
    __shared__ int cnt[NB1];
    int t = threadIdx.x, blk = blockIdx.x;
    for (int i = t; i < NB1; i += 256) cnt[i] = 0;
    __syncthreads();
    int base = blk * EPB;
    for (int i = t; i < EPB; i += 256) atomicAdd(&cnt[dst[base + i] >> 8], 1);
    __syncthreads();
    for (int b = t; b < NB1; b += 256) bh[b * BLK1 + blk] = cnt[b];   // bucket-major
}

// pack = src (17 bits) | dst_local (8 bits) << 17
__global__ __launch_bounds__(256) void k_p2(int2* __restrict__ tmp, const int* __restrict__ obh,
                                            const int* __restrict__ src,
                                            const int* __restrict__ dst,
                                            const float* __restrict__ ew) {
    __shared__ int cur[NB1];
    int t = threadIdx.x, blk = blockIdx.x;
    for (int b = t; b < NB1; b += 256) cur[b] = obh[b * BLK1 + blk];
    __syncthreads();
    int base = blk * EPB;
    for (int i = t; i < EPB; i += 256) {
        int e = base + i;
        int d = dst[e];
        int pos = atomicAdd(&cur[d >> 8], 1);
        tmp[pos] = make_int2(src[e] | ((d & 255) << 17), __float_as_int(ew[e]));
    }
}

__global__ __launch_bounds__(256) void k_p3a(int* __restrict__ deg, float* __restrict__ dinv,
                                             const int2* __restrict__ tmp,
                                             const int* __restrict__ obh) {
    __shared__ int h[NPB];
    __shared__ float ws[NPB];
    int t = threadIdx.x, b = blockIdx.x;
    for (int i = t; i < NPB; i += 256) { h[i] = 0; ws[i] = 0.f; }
    __syncthreads();
    int a  = obh[b * BLK1];
    int e_ = (b == NB1 - 1) ? E1 : obh[(b + 1) * BLK1];
    for (int i = a + t; i < e_; i += 256) {
        int2 ed = tmp[i];
        int dl = (ed.x >> 17) & 255;
        atomicAdd(&h[dl], 1);
        atomicAdd(&ws[dl], __int_as_float(ed.y));
    }
    __syncthreads();
    for (int i = t; i < NPB; i += 256) {
        deg[b * NPB + i] = h[i];
        dinv[b * NPB + i] = rsqrtf(1.f + ws[i]);
    }
}

__global__ __launch_bounds__(256) void k_p3b(int2* __restrict__ edges,
                                             const int2* __restrict__ tmp,
                                             const int* __restrict__ obh,
                                             const int* __restrict__ row,
                                             const float* __restrict__ dinv) {
    __shared__ int cur[NPB];
    __shared__ float dvl[NPB];
    int t = threadIdx.x, b = blockIdx.x;
    int n0 = b * NPB;
    for (int i = t; i < NPB; i += 256) {
        cur[i] = row[n0 + i];
        dvl[i] = dinv[n0 + i];
    }
    __syncthreads();
    int a  = obh[b * BLK1];
    int e_ = (b == NB1 - 1) ? E1 : obh[(b + 1) * BLK1];
    for (int i = a + t; i < e_; i += 256) {
        int2 ed = tmp[i];
        int dl = (ed.x >> 17) & 255;
        int s = ed.x & 0x1FFFF;
        int pos = atomicAdd(&cur[dl], 1);
        float w = dinv[s] * __int_as_float(ed.y) * dvl[dl];
        edges[pos] = make_int2(s, __float_as_int(w));
    }
}

// ---------------- dense ops ----------------

// out_bf16[n][64] = x[n][K] @ W[K][64]. Block: 256 rows x 64 cols; tile 8x8.
// Output stored as bf16 (halves the conv gather volume).
template <int K>
__global__ __launch_bounds__(256) void k_gemm(unsigned short* __restrict__ out,
                                              const float* __restrict__ x,
                                              const float* __restrict__ W, int n) {
    __shared__ float Wl[32 * 64];       // [kk][col]
    __shared__ float xs[256 * 37];      // [r][kk], stride 37
    int tid = threadIdx.x;
    int row0 = blockIdx.x * 256;
    int r0 = (tid >> 3) * 8;
    int c0 = (tid & 7) * 8;
    float acc[8][8];
#pragma unroll
    for (int i = 0; i < 8; i++)
#pragma unroll
        for (int j = 0; j < 8; j++) acc[i][j] = 0.f;

    for (int k0 = 0; k0 < K; k0 += 32) {
        __syncthreads();
        {
            const float4* W4 = (const float4*)(W + k0 * 64);
            float4* Wl4 = (float4*)Wl;
#pragma unroll
            for (int i = 0; i < 2; i++) Wl4[tid + i * 256] = W4[tid + i * 256];
        }
#pragma unroll
        for (int i = 0; i < 8; i++) {
            int idx = tid + i * 256;
            int r = idx >> 3, kq = idx & 7;
            float4 v = make_float4(0.f, 0.f, 0.f, 0.f);
            if (row0 + r < n)
                v = *(const float4*)(x + (size_t)(row0 + r) * K + k0 + kq * 4);
            xs[r * 37 + kq * 4 + 0] = v.x;
            xs[r * 37 + kq * 4 + 1] = v.y;
            xs[r * 37 + kq * 4 + 2] = v.z;
            xs[r * 37 + kq * 4 + 3] = v.w;
        }
        __syncthreads();
#pragma unroll 2
        for (int kk = 0; kk < 32; kk++) {
            float4 wlo = *(const float4*)(&Wl[kk * 64 + c0]);
            float4 whi = *(const float4*)(&Wl[kk * 64 + c0 + 4]);
            float xf[8];
#pragma unroll
            for (int i = 0; i < 8; i++) xf[i] = xs[(r0 + i) * 37 + kk];
#pragma unroll
            for (int i = 0; i < 8; i++) {
                acc[i][0] += xf[i] * wlo.x; acc[i][1] += xf[i] * wlo.y;
                acc[i][2] += xf[i] * wlo.z; acc[i][3] += xf[i] * wlo.w;
                acc[i][4] += xf[i] * whi.x; acc[i][5] += xf[i] * whi.y;
                acc[i][6] += xf[i] * whi.z; acc[i][7] += xf[i] * whi.w;
            }
        }
    }
#pragma unroll
    for (int i = 0; i < 8; i++) {
        int row = row0 + r0 + i;
        if (row < n) {
            uint4 o;
            o.x = (unsigned int)f2bf(acc[i][0]) | ((unsigned int)f2bf(acc[i][1]) << 16);
            o.y = (unsigned int)f2bf(acc[i][2]) | ((unsigned int)f2bf(acc[i][3]) << 16);
            o.z = (unsigned int)f2bf(acc[i][4]) | ((unsigned int)f2bf(acc[i][5]) << 16);
            o.w = (unsigned int)f2bf(acc[i][6]) | ((unsigned int)f2bf(acc[i][7]) << 16);
            *(uint4*)(out + (size_t)row * 64 + c0) = o;
        }
    }
}

// fused GCN aggregate: wave per dst node, lane = feature column, 8-deep ILP.
// Gathers bf16 h (128 B/row), accumulates fp32, writes fp32.
__global__ __launch_bounds__(256) void k_conv(float* __restrict__ out,
                                              const unsigned short* __restrict__ h,
                                              const int2* __restrict__ edges,
                                              const int* __restrict__ row,
                                              const float* __restrict__ dinv,
                                              const float* __restrict__ bias, int n) {
    int d = blockIdx.x * 4 + (threadIdx.x >> 6);
    if (d >= n) return;
    int lane = threadIdx.x & 63;
    int a = row[d], b = row[d + 1];
    float acc[8] = {0.f, 0.f, 0.f, 0.f, 0.f, 0.f, 0.f, 0.f};
    for (int base = a; base < b; base += 64) {
        int m = b - base; if (m > 64) m = 64;
        int sv = 0, wv = 0;
        if (base + lane < b) { int2 e = edges[base + lane]; sv = e.x; wv = e.y; }
        int j = 0;
        for (; j + 7 < m; j += 8) {
#pragma unroll
            for (int q = 0; q < 8; q++) {
                int s = __shfl(sv, j + q);
                float w = __int_as_float(__shfl(wv, j + q));
                acc[q] += bf2f(h[(size_t)s * HID + lane]) * w;
            }
        }
        for (; j < m; j++) {
            int s = __shfl(sv, j);
            float w = __int_as_float(__shfl(wv, j));
            acc[0] += bf2f(h[(size_t)s * HID + lane]) * w;
        }
    }
    float di = dinv[d];
    float v = ((acc[0] + acc[1]) + (acc[2] + acc[3])) + ((acc[4] + acc[5]) + (acc[6] + acc[7]))
              + bf2f(h[(size_t)d * HID + lane]) * di * di + bias[lane];
    out[(size_t)d * HID + lane] = v > 0.f ? v : 0.f;
}

// segment-mean pool: wave per segment; counts from rowptr diff.
__global__ __launch_bounds__(256) void k_pool(float* __restrict__ emb, float* __restrict__ esum,
                                              const float* __restrict__ embo,
                                              const float* __restrict__ h,
                                              const int* __restrict__ nodeid,
                                              const int* __restrict__ segrow) {
    int s = blockIdx.x * 4 + (threadIdx.x >> 6);
    if (s >= NSEG) return;
    int lane = threadIdx.x & 63;
    int a = segrow[s], b = segrow[s + 1];
    float ac0 = 0.f, ac1 = 0.f, ac2 = 0.f, ac3 = 0.f;
    for (int base = a; base < b; base += 64) {
        int m = b - base; if (m > 64) m = 64;
        int nid = 0;
        if (base + lane < b) nid = nodeid[base + lane];
        int j = 0;
        for (; j + 3 < m; j += 4) {
            int n0 = __shfl(nid, j),     n1 = __shfl(nid, j + 1);
            int n2 = __shfl(nid, j + 2), n3 = __shfl(nid, j + 3);
            ac0 += h[(size_t)n0 * HID + lane];
            ac1 += h[(size_t)n1 * HID + lane];
            ac2 += h[(size_t)n2 * HID + lane];
            ac3 += h[(size_t)n3 * HID + lane];
        }
        for (; j < m; j++) {
            int n0 = __shfl(nid, j);
            ac0 += h[(size_t)n0 * HID + lane];
        }
    }
    float mean = ((ac0 + ac1) + (ac2 + ac3)) / fmaxf((float)(b - a), 1.0f);
    emb[(size_t)s * HID + lane] = mean;
    if (esum) esum[(size_t)s * HID + lane] = mean + embo[(size_t)s * HID + lane];
}

// ---------------- classifier ----------------

__global__ __launch_bounds__(256) void k_cls(float* __restrict__ part_,
                                             const float* __restrict__ s,
                                             const float* __restrict__ Wm1) {
    __shared__ float sl[KCC * 16];      // [kk][b]
    int tid = threadIdx.x;
    int kt = blockIdx.x >> 2, ct = blockIdx.x & 3;
    int k0 = kt * KCC;
    for (int i = tid; i < KCC * 16; i += 256) {
        int kk = i & (KCC - 1), b = i >> 7;        // coalesced over kk
        sl[kk * 16 + b] = s[b * SDIM + k0 + kk];
    }
    __syncthreads();
    int c = ct * 256 + tid;
    bool active = c < CLS;
    float acc[16];
#pragma unroll
    for (int b = 0; b < 16; b++) acc[b] = 0.f;
    const float* wp = Wm1 + (size_t)k0 * CLS + c;
#pragma unroll 2
    for (int kk = 0; kk < KCC; kk++) {
        float w = active ? wp[(size_t)kk * CLS] : 0.f;
        float4 s0 = *(const float4*)(&sl[kk * 16 + 0]);
        float4 s1 = *(const float4*)(&sl[kk * 16 + 4]);
        float4 s2 = *(const float4*)(&sl[kk * 16 + 8]);
        float4 s3 = *(const float4*)(&sl[kk * 16 + 12]);
        acc[0]  += s0.x * w; acc[1]  += s0.y * w; acc[2]  += s0.z * w; acc[3]  += s0.w * w;
        acc[4]  += s1.x * w; acc[5]  += s1.y * w; acc[6]  += s1.z * w; acc[7]  += s1.w * w;
        acc[8]  += s2.x * w; acc[9]  += s2.y * w; acc[10] += s2.z * w; acc[11] += s2.w * w;
        acc[12] += s3.x * w; acc[13] += s3.y * w; acc[14] += s3.z * w; acc[15] += s3.w * w;
    }
    float* pp = part_ + (size_t)(kt * CT1 + ct) * 16 * 256;
#pragma unroll
    for (int b = 0; b < 16; b++) pp[b * 256 + tid] = acc[b];
}

// reduce partials + BatchNorm + LeakyReLU in one pass
__global__ void k_credbn(float* __restrict__ hact, const float* __restrict__ part_,
                         const float* __restrict__ bm1, const float* __restrict__ gamma,
                         const float* __restrict__ beta, const float* __restrict__ mean,
                         const float* __restrict__ var) {
    int idx = blockIdx.x * 256 + threadIdx.x;
    if (idx >= BSZ * CLS) return;
    int b = idx / CLS, c = idx % CLS;
    int ct = c >> 8, cl = c & 255;
    float sum = 0.f;
#pragma unroll 2
    for (int kt = 0; kt < KT1; kt++)
        sum += part_[((size_t)(kt * CT1 + ct) * 16 + b) * 256 + cl];
    float t = sum + bm1[c];
    t = gamma[c] * (t - mean[c]) * rsqrtf(var[c] + 1e-5f) + beta[c];
    hact[idx] = t > 0.f ? t : 0.01f * t;
}

__global__ void k_out(float* __restrict__ outp, const float* __restrict__ hact,
                      const float* __restrict__ Wm2, const float* __restrict__ bm2) {
    int tid = threadIdx.x;              // one block of 256
    int oi = tid >> 3, part = tid & 7;  // 32 outputs x 8 partials
    int b = oi >> 1, o = oi & 1;
    float acc = (part == 0) ? bm2[o] : 0.f;
    for (int k = part; k < CLS; k += 8) acc += hact[b * CLS + k] * Wm2[k * OCH + o];
    unsafeAtomicAdd(&outp[b * OCH + o], acc);
}

extern "C" void kernel_launch(void* const* d_in, const int* in_sizes, int n_in,
                              void* d_out, int out_size, void* d_ws, size_t ws_size,
                              hipStream_t stream) {
    const float* x1  = (const float*)d_in[0];
    const int*   nl  = (const int*)d_in[1];
    const int*   ei1 = (const int*)d_in[2];
    const float* ew1 = (const float*)d_in[3];
    const int*   ba1 = (const int*)d_in[4];
    const float* x2  = (const float*)d_in[5];
    const int*   rl  = (const int*)d_in[6];
    const int*   ei2 = (const int*)d_in[7];
    const float* ew2 = (const float*)d_in[8];
    const int*   ba2 = (const int*)d_in[9];
    const float* W1a = (const float*)d_in[10];
    const float* b1a = (const float*)d_in[11];
    const float* W1b = (const float*)d_in[12];
    const float* b1b = (const float*)d_in[13];
    const float* W2a = (const float*)d_in[14];
    const float* b2a = (const float*)d_in[15];
    const float* W2b = (const float*)d_in[16];
    const float* b2b = (const float*)d_in[17];
    const float* Wm1 = (const float*)d_in[18];
    const float* bm1 = (const float*)d_in[19];
    const float* gam = (const float*)d_in[20];
    const float* bet = (const float*)d_in[21];
    const float* bmn = (const float*)d_in[22];
    const float* bvr = (const float*)d_in[23];
    const float* Wm2 = (const float*)d_in[24];
    const float* bm2 = (const float*)d_in[25];

    float* out  = (float*)d_out;
    float* emb1 = out + 32;               // embedding        (16 x 9472)
    float* emb2 = emb1 + NSEG * HID;      // embedding_roi
    float* esum = emb2 + NSEG * HID;      // embedding + embedding_roi

    // ---- workspace carve ----
    char* p = (char*)d_ws;
    auto carve = [&](size_t nbytes) { char* q = p; p += (nbytes + 255) & ~(size_t)255; return (void*)q; };
    int*            row1    = (int*)   carve((N1 + 1) * 4);
    int2*           edges1  = (int2*)  carve((size_t)E1 * 8);
    float*          dinv1   = (float*) carve(N1 * 4);
    unsigned short* A1b     = (unsigned short*)carve((size_t)N1 * HID * 2);  // bf16 h
    float*          B1      = (float*) carve((size_t)N1 * HID * 4);
    int*            nodeid1 = (int*)   carve(N1 * 4);
    int*            segrow1 = (int*)   carve((NSEG + 1) * 4);
    int*            segoff1 = (int*)   carve(NSEG * 4);
    int*            bh      = (int*)   carve((NB1 * BLK1 + 1) * 4);
    int*            obh     = (int*)   carve((NB1 * BLK1 + 1) * 4);
    int*            deg     = (int*)   carve(N1 * 4);
    int*            row2    = (int*)   carve((N2 + 1) * 4);
    int*            off2    = (int*)   carve(N2 * 4);
    int2*           edges2  = (int2*)  carve((size_t)E2 * 8);
    float*          dinv2   = (float*) carve(N2 * 4);
    unsigned short* A2b     = (unsigned short*)carve((size_t)N2 * HID * 2);
    float*          B2      = (float*) carve((size_t)N2 * HID * 4);
    int*            nodeid2 = (int*)   carve(N2 * 4);
    int*            segrow2 = (int*)   carve((NSEG + 1) * 4);
    int*            segoff2 = (int*)   carve(NSEG * 4);
    int*            part    = (int*)   carve(256 * 4);
    float*          hact    = (float*) carve(BSZ * CLS * 4);
    int2* tmp1 = (int2*)B1;   // 16.8 MB aliases B1 (33.5 MB): CSR build done
                              // before conv1's first B1 write
    float* clsp = B1;         // 4.85 MB partial slabs alias B1: B1 dead after last k_pool

    const int* src1 = ei1;
    const int* dst1 = ei1 + E1;
    const int* src2 = ei2;
    const int* dst2 = ei2 + E2;

    hipMemsetAsync(d_out, 0, (size_t)out_size * sizeof(float), stream);

    // ---------------- graph 2 (ROI graph, small) ----------------
    hipMemsetAsync(off2, 0, N2 * 4, stream);
    k_hist_dst<<<(E2 + 255) / 256, 256, 0, stream>>>(off2, dst2, E2);
    k_scan_one<<<1, 256, 0, stream>>>(off2, row2, N2);
    hipMemcpyAsync(off2, row2, N2 * 4, hipMemcpyDeviceToDevice, stream);
    k_fill_edges<<<(E2 + 255) / 256, 256, 0, stream>>>(edges2, off2, src2, dst2, ew2, E2);
    k_deg_dinv<<<(N2 + 255) / 256, 256, 0, stream>>>(dinv2, row2, edges2, N2);
    k_scale<<<(N2 + 255) / 256, 256, 0, stream>>>(edges2, row2, dinv2, N2);

    k_gemm<INCH><<<(N2 + 255) / 256, 256, 0, stream>>>(A2b, x2, W2a, N2);
    k_conv<<<(N2 + 3) / 4, 256, 0, stream>>>(B2, A2b, edges2, row2, dinv2, b2a, N2);
    k_gemm<HID><<<(N2 + 255) / 256, 256, 0, stream>>>(A2b, B2, W2b, N2);
    k_conv<<<(N2 + 3) / 4, 256, 0, stream>>>(B2, A2b, edges2, row2, dinv2, b2b, N2);
    // graph-2 final features now in B2 (fp32)

    hipMemsetAsync(segoff2, 0, NSEG * 4, stream);
    k_hist_seg<<<(N2 + 255) / 256, 256, 0, stream>>>(segoff2, ba2, rl, N2);
    k_scan_one<<<1, 256, 0, stream>>>(segoff2, segrow2, NSEG);
    hipMemcpyAsync(segoff2, segrow2, NSEG * 4, hipMemcpyDeviceToDevice, stream);
    k_fill_seg<<<(N2 + 255) / 256, 256, 0, stream>>>(nodeid2, segoff2, ba2, rl, N2);
    k_pool<<<(NSEG + 3) / 4, 256, 0, stream>>>(emb2, (float*)nullptr, (const float*)nullptr,
                                               B2, nodeid2, segrow2);

    // ---------------- graph 1: radix-partition CSR build ----------------
    k_p1<<<BLK1, 256, 0, stream>>>(bh, dst1);
    k_scan1<<<(NB1 * BLK1 + 1023) / 1024, 256, 0, stream>>>(bh, obh, part, NB1 * BLK1);
    k_scan2<<<1, 256, 0, stream>>>(part, (NB1 * BLK1 + 1023) / 1024);
    k_scan3<<<(NB1 * BLK1 + 255) / 256, 256, 0, stream>>>(obh, part, NB1 * BLK1, E1);
    k_p2<<<BLK1, 256, 0, stream>>>(tmp1, obh, src1, dst1, ew1);
    k_p3a<<<NB1, 256, 0, stream>>>(deg, dinv1, tmp1, obh);
    k_scan1<<<(N1 + 1023) / 1024, 256, 0, stream>>>(deg, row1, part, N1);
    k_scan2<<<1, 256, 0, stream>>>(part, (N1 + 1023) / 1024);
    k_scan3<<<(N1 + 255) / 256, 256, 0, stream>>>(row1, part, N1, E1);
    k_p3b<<<NB1, 256, 0, stream>>>(edges1, tmp1, obh, row1, dinv1);

    // ---------------- graph 1: convs ----------------
    k_gemm<INCH><<<N1 / 256, 256, 0, stream>>>(A1b, x1, W1a, N1);
    k_conv<<<(N1 + 3) / 4, 256, 0, stream>>>(B1, A1b, edges1, row1, dinv1, b1a, N1);
    k_gemm<HID><<<N1 / 256, 256, 0, stream>>>(A1b, B1, W1b, N1);
    k_conv<<<(N1 + 3) / 4, 256, 0, stream>>>(B1, A1b, edges1, row1, dinv1, b1b, N1);

    hipMemsetAsync(segoff1, 0, NSEG * 4, stream);
    k_hist_seg<<<(N1 + 255) / 256, 256, 0, stream>>>(segoff1, ba1, nl, N1);
    k_scan_one<<<1, 256, 0, stream>>>(segoff1, segrow1, NSEG);
    hipMemcpyAsync(segoff1, segrow1, NSEG * 4, hipMemcpyDeviceToDevice, stream);
    k_fill_seg<<<(N1 + 255) / 256, 256, 0, stream>>>(nodeid1, segoff1, ba1, nl, N1);
    k_pool<<<(NSEG + 3) / 4, 256, 0, stream>>>(emb1, esum, emb2, B1, nodeid1, segrow1);
    // B1 dead from here; clsp aliases it

    // ---------------- classifier ----------------
    k_cls<<<KT1 * CT1, 256, 0, stream>>>(clsp, esum, Wm1);
    k_credbn<<<(BSZ * CLS + 255) / 256, 256, 0, stream>>>(hact, clsp, bm1, gam, bet, bmn, bvr);
    k_out<<<1, 256, 0, stream>>>(out, hact, Wm2, bm2);
}